// Round 7
// baseline (14223.245 us; speedup 1.0000x reference)
//
#include <hip/hip_runtime.h>
#include <hip/hip_bf16.h>

#define T_STEPS 128
#define DH      512
#define NPATCH  196
#define BATCH   16
#define VOCAB   10000
#define NB      256   // persistent grid size

typedef __attribute__((ext_vector_type(8))) short bf16x8;
typedef __attribute__((ext_vector_type(4))) float f32x4;

__device__ __forceinline__ float sigm(float x) { return 1.0f / (1.0f + __expf(-x)); }
__device__ __forceinline__ float ftanh(float x) {
    float e = __expf(2.0f * x);
    return 1.0f - 2.0f / (e + 1.0f);
}
__device__ __forceinline__ unsigned short f2b(float x) {
    union { float f; unsigned u; } v; v.f = x;
    unsigned r = (v.u + 0x7FFFu + ((v.u >> 16) & 1u)) >> 16;
    return (unsigned short)r;
}
__device__ __forceinline__ float b2f(unsigned short h) {
    union { unsigned u; float f; } v; v.u = ((unsigned)h) << 16;
    return v.f;
}

// ---------------- conversion kernels ----------------
__global__ __launch_bounds__(256)
void cvt_kernel(const float* __restrict__ src, unsigned short* __restrict__ dst, int n)
{
    int i = (blockIdx.x * 256 + threadIdx.x) * 8;
    if (i >= n) return;
    float4 v0 = *(const float4*)(src + i);
    float4 v1 = *(const float4*)(src + i + 4);
    float xs[8] = {v0.x, v0.y, v0.z, v0.w, v1.x, v1.y, v1.z, v1.w};
    bf16x8 o;
#pragma unroll
    for (int j = 0; j < 8; ++j) o[j] = (short)f2b(xs[j]);
    *(bf16x8*)(dst + i) = o;
}

__global__ __launch_bounds__(256)
void cvt_split_kernel(const float* __restrict__ src, unsigned short* __restrict__ hi,
                      unsigned short* __restrict__ lo, int n)
{
    int i = (blockIdx.x * 256 + threadIdx.x) * 8;
    if (i >= n) return;
    float4 v0 = *(const float4*)(src + i);
    float4 v1 = *(const float4*)(src + i + 4);
    float xs[8] = {v0.x, v0.y, v0.z, v0.w, v1.x, v1.y, v1.z, v1.w};
    bf16x8 h_, l_;
#pragma unroll
    for (int j = 0; j < 8; ++j) {
        unsigned short hb = f2b(xs[j]);
        float r = xs[j] - b2f(hb);
        h_[j] = (short)hb;
        l_[j] = (short)f2b(r);
    }
    *(bf16x8*)(hi + i) = h_;
    *(bf16x8*)(lo + i) = l_;
}

// ---------------- MFMA GEMM (3-term split; verified round 4) ----------------
__global__ __launch_bounds__(256)
void gemm_mfma(const unsigned short* __restrict__ AH, const unsigned short* __restrict__ AL,
               const unsigned short* __restrict__ WH, const unsigned short* __restrict__ WL,
               const float* __restrict__ bias, float* __restrict__ C,
               unsigned short* __restrict__ CbH, unsigned short* __restrict__ CbL,
               int M, int N, int K)
{
    const int tid = threadIdx.x, wid = tid >> 6, l = tid & 63;
    const int m0 = blockIdx.x * 128 + (wid >> 1) * 64;
    const int n0 = blockIdx.y * 128 + (wid & 1) * 64;
    const int lm = l & 15, lk = (l >> 4) * 8;
    f32x4 acc[4][4];
#pragma unroll
    for (int i = 0; i < 4; ++i)
#pragma unroll
        for (int j = 0; j < 4; ++j) acc[i][j] = (f32x4){0.f, 0.f, 0.f, 0.f};
    const bf16x8 az = {0,0,0,0,0,0,0,0};

    for (int k0 = 0; k0 < K; k0 += 32) {
        bf16x8 aH[4], aL[4];
#pragma unroll
        for (int mi = 0; mi < 4; ++mi) {
            int m = m0 + mi * 16 + lm;
            aH[mi] = (m < M) ? *(const bf16x8*)(AH + (size_t)m * K + k0 + lk) : az;
            aL[mi] = (AL && m < M) ? *(const bf16x8*)(AL + (size_t)m * K + k0 + lk) : az;
        }
#pragma unroll
        for (int ni = 0; ni < 4; ++ni) {
            int n = n0 + ni * 16 + lm;
            bf16x8 bH = az, bL = az;
            if (n < N) {
                bH = *(const bf16x8*)(WH + (size_t)n * K + k0 + lk);
                if (WL) bL = *(const bf16x8*)(WL + (size_t)n * K + k0 + lk);
            }
#pragma unroll
            for (int mi = 0; mi < 4; ++mi) {
                acc[mi][ni] = __builtin_amdgcn_mfma_f32_16x16x32_bf16(aH[mi], bH, acc[mi][ni], 0, 0, 0);
                if (WL) acc[mi][ni] = __builtin_amdgcn_mfma_f32_16x16x32_bf16(aH[mi], bL, acc[mi][ni], 0, 0, 0);
                if (AL) acc[mi][ni] = __builtin_amdgcn_mfma_f32_16x16x32_bf16(aL[mi], bH, acc[mi][ni], 0, 0, 0);
            }
        }
    }
    const int rr = (l >> 4) * 4;
#pragma unroll
    for (int mi = 0; mi < 4; ++mi) {
        int mb = m0 + mi * 16 + rr;
#pragma unroll
        for (int ni = 0; ni < 4; ++ni) {
            int n = n0 + ni * 16 + lm;
            if (n < N) {
                float bs = bias ? bias[n] : 0.f;
#pragma unroll
                for (int r = 0; r < 4; ++r) {
                    int mm = mb + r;
                    if (mm < M) {
                        float v = acc[mi][ni][r] + bs;
                        if (C)   C[(size_t)mm * N + n] = v;
                        if (CbH) {
                            unsigned short hb = f2b(v);
                            CbH[(size_t)mm * N + n] = hb;
                            if (CbL) CbL[(size_t)mm * N + n] = f2b(v - b2f(hb));
                        }
                    }
                }
            }
        }
    }
}

// ---------------- h0 / c0 (all fp32) ----------------
__global__ __launch_bounds__(256)
void h0c0_kernel(const float* __restrict__ cls,
                 const float* __restrict__ ihw, const float* __restrict__ ihb,
                 const float* __restrict__ icw, const float* __restrict__ icb,
                 float* __restrict__ c_g, float* __restrict__ h_raw, float* __restrict__ hln)
{
    int id = blockIdx.x * 256 + threadIdx.x;   // 0..16383
    int which = id >> 13;
    int b = (id >> 9) & 15;
    int d = id & 511;
    const float* w = (which ? icw : ihw) + d * 768;
    const float* x = cls + b * 768;
    float acc = which ? icb[d] : ihb[d];
    const float4* x4 = (const float4*)x;
    const float4* w4 = (const float4*)w;
#pragma unroll 4
    for (int k = 0; k < 192; ++k) {
        float4 a = x4[k], ww = w4[k];
        acc += a.x * ww.x + a.y * ww.y + a.z * ww.z + a.w * ww.w;
    }
    if (which) c_g[b * 512 + d] = acc;
    else { h_raw[b * 512 + d] = acc; hln[b * 512 + d] = acc; }
}

// ---------------- embedding gather (fp32) ----------------
__global__ __launch_bounds__(256)
void gather_kernel(const int* __restrict__ ids, const float* __restrict__ emb,
                   float* __restrict__ x_all)
{
    int q = blockIdx.x * 256 + threadIdx.x;    // 2048 rows * 128 float4
    if (q >= 2048 * 128) return;
    int r = q >> 7, kq = q & 127;
    int tgt = ids[r];
    ((float4*)x_all)[(size_t)r * 128 + kq] = ((const float4*)emb)[(size_t)tgt * 128 + kq];
}

// ---------------- grid barrier (AGENT-scope atomics; all NB blocks resident) ----------------
// cnt and flag are BOTH zeroed by the 512-byte memset every kernel_launch call
// (flag lives at byte offset 256 — previous round memset only 256 bytes, leaving the
// flag at its end-of-run value 512 on graph replays => barriers no-op'd => deadlock).
__device__ __forceinline__ void grid_barrier(int* cnt, int* flag, int& gen)
{
    __syncthreads();
    if (threadIdx.x == 0) {
        int g = gen;
        int t = __hip_atomic_fetch_add(cnt, 1, __ATOMIC_ACQ_REL, __HIP_MEMORY_SCOPE_AGENT);
        if (t == NB - 1) {
            __hip_atomic_store(cnt, 0, __ATOMIC_RELAXED, __HIP_MEMORY_SCOPE_AGENT);
            __hip_atomic_store(flag, g + 1, __ATOMIC_RELEASE, __HIP_MEMORY_SCOPE_AGENT);
        } else {
            while (__hip_atomic_load(flag, __ATOMIC_ACQUIRE, __HIP_MEMORY_SCOPE_AGENT) < g + 1)
                __builtin_amdgcn_s_sleep(4);
        }
        gen = g + 1;
    }
    __syncthreads();
}

// ---------------- persistent recurrence kernel ----------------
// 256 blocks x 256 threads. Block k owns d-pair {2k,2k+1}: gate-weight rows (fp32, LDS,
// loaded once), Wh rows e={2k,2k+1}, LSTM cell state for its d's.
// Per step: S1 LN+ew | S2 scores | S3 softmax+ctx | S4 gates+cell, 4 grid barriers.
__global__ __launch_bounds__(256)
void recur_kernel(const float* __restrict__ x_all, float* __restrict__ ctx,
                  float* __restrict__ hln, float* __restrict__ h_raw,
                  float* __restrict__ c_g, float* __restrict__ ew_g,
                  float* __restrict__ sc_g, float* __restrict__ partials,
                  const float* __restrict__ keys, const float* __restrict__ keysWk,
                  const float* __restrict__ Wih, const float* __restrict__ Whh,
                  const float* __restrict__ bih, const float* __restrict__ bhh,
                  const float* __restrict__ Wh, const float* __restrict__ lng,
                  const float* __restrict__ lnb, const float* __restrict__ vvec,
                  unsigned short* __restrict__ h_all_b,
                  int* bar_cnt, int* bar_flag)
{
    __shared__ float Wg[8][1544];     // 8 gate rows x [Wih(1024)|Whh(512)] fp32
    __shared__ float zbuf[2][1544];   // staged z=[x|ctx|hln] for 2 batches
    __shared__ float alpha_l[256];
    __shared__ float pbuf[8][32];
    __shared__ float mu_s[16], rr_s[16], sm4[8], gbuf[2][8], bias8[8];
    const int k = blockIdx.x, tid = threadIdx.x;

    // setup: load this block's gate-weight rows (once; 48KB/block, 12MB chip-wide)
    for (int r = 0; r < 8; ++r) {
        int g = r >> 1, dd = r & 1, j = g * 512 + 2 * k + dd;
        for (int off = tid; off < 1536; off += 256)
            Wg[r][off] = (off < 1024) ? Wih[(size_t)j * 1024 + off]
                                      : Whh[(size_t)j * 512 + (off - 1024)];
        if (tid == 0) bias8[r] = bih[j] + bhh[j];
    }
    __syncthreads();

    int gen = 0;
    for (int t = 0; t < T_STEPS; ++t) {
        // ===== S1: LN scalars (t>0) + hln/h_all own-d writes + ew e-pair =====
        if (t > 0) {
            int b = tid >> 4, i = tid & 15;
            float s1 = 0.f, s2 = 0.f;
            const float* pp = partials + ((size_t)b * NB + i * 16) * 2;
#pragma unroll 4
            for (int q = 0; q < 16; ++q) { s1 += pp[q * 2]; s2 += pp[q * 2 + 1]; }
#pragma unroll
            for (int m = 1; m < 16; m <<= 1) { s1 += __shfl_xor(s1, m); s2 += __shfl_xor(s2, m); }
            if (i == 0) {
                float muv = s1 * (1.f / 512.f);
                float varv = s2 * (1.f / 512.f) - muv * muv;
                mu_s[b] = muv; rr_s[b] = rsqrtf(varv + 1e-5f);
            }
        }
        __syncthreads();
        if (t > 0 && tid < 32) {
            int b = tid >> 1, dd = tid & 1, d = 2 * k + dd;
            float hr = h_raw[b * 512 + d];
            float val = (hr - mu_s[b]) * rr_s[b] * lng[d] + lnb[d];
            hln[b * 512 + d] = val;
            h_all_b[((size_t)b * T_STEPS + (t - 1)) * 512 + d] = f2b(val);
        }
        {   // ew[b][e] for e in {2k,2k+1}: 32 dots x 8 segs
            int dot = tid >> 3, seg = tid & 7;
            int b = dot >> 1, e = 2 * k + (dot & 1);
            const float4* wrow = (const float4*)(Wh + (size_t)e * 512);
            const float4* hrow = (const float4*)(h_raw + b * 512);
            const float4* g4 = (const float4*)lng;
            const float4* b4 = (const float4*)lnb;
            float muv = 0.f, rv = 1.f;
            if (t > 0) { muv = mu_s[b]; rv = rr_s[b]; }
            float s = 0.f;
            for (int i = 0; i < 16; ++i) {
                int k4 = seg + i * 8;
                float4 hv = hrow[k4], w4 = wrow[k4];
                if (t > 0) {
                    float4 gg = g4[k4], bb = b4[k4];
                    hv.x = (hv.x - muv) * rv * gg.x + bb.x;
                    hv.y = (hv.y - muv) * rv * gg.y + bb.y;
                    hv.z = (hv.z - muv) * rv * gg.z + bb.z;
                    hv.w = (hv.w - muv) * rv * gg.w + bb.w;
                }
                s += hv.x * w4.x + hv.y * w4.y + hv.z * w4.z + hv.w * w4.w;
            }
#pragma unroll
            for (int m = 1; m < 8; m <<= 1) s += __shfl_xor(s, m);
            if (seg == 0) ew_g[b * 512 + e] = s;
        }
        grid_barrier(bar_cnt, bar_flag, gen);

        // ===== S2: scores[b][n] = v . tanh(ew[b] + keysWk[b][n]) =====
        {
            int wv = tid >> 6, lane = tid & 63;
#pragma unroll
            for (int rd = 0; rd < 4; ++rd) {
                int p = (k * 4 + wv) + 1024 * rd;
                if (p < BATCH * NPATCH) {
                    int b = p / NPATCH, n = p - b * NPATCH;
                    const float4* ew4 = (const float4*)(ew_g + b * 512) + lane * 2;
                    const float4* kw4 = (const float4*)(keysWk + (size_t)(b * NPATCH + n) * 512) + lane * 2;
                    const float4* vv4 = (const float4*)vvec + lane * 2;
                    float s = 0.f;
#pragma unroll
                    for (int u = 0; u < 2; ++u) {
                        float4 e4 = ew4[u], kk = kw4[u], v4 = vv4[u];
                        s += ftanh(e4.x + kk.x) * v4.x + ftanh(e4.y + kk.y) * v4.y
                           + ftanh(e4.z + kk.z) * v4.z + ftanh(e4.w + kk.w) * v4.w;
                    }
#pragma unroll
                    for (int m = 1; m < 64; m <<= 1) s += __shfl_xor(s, m);
                    if (lane == 0) sc_g[b * NPATCH + n] = s;
                }
            }
        }
        grid_barrier(bar_cnt, bar_flag, gen);

        // ===== S3: softmax (redundant per block) + ctx 32-d slice =====
        {
            int b = k >> 4, d0 = (k & 15) * 32;
            float sv = (tid < NPATCH) ? sc_g[b * NPATCH + tid] : -1e30f;
            float mx = sv;
#pragma unroll
            for (int m = 1; m < 64; m <<= 1) mx = fmaxf(mx, __shfl_xor(mx, m));
            if ((tid & 63) == 0) sm4[tid >> 6] = mx;
            __syncthreads();
            mx = fmaxf(fmaxf(sm4[0], sm4[1]), fmaxf(sm4[2], sm4[3]));
            float ev = (tid < NPATCH) ? __expf(sv - mx) : 0.f;
            alpha_l[tid] = ev;
            float sum = ev;
#pragma unroll
            for (int m = 1; m < 64; m <<= 1) sum += __shfl_xor(sum, m);
            if ((tid & 63) == 0) sm4[4 + (tid >> 6)] = sum;
            __syncthreads();
            float inv = 1.f / (sm4[4] + sm4[5] + sm4[6] + sm4[7]);
            int dl = tid & 31, g8 = tid >> 5;
            float acc = 0.f;
            for (int n = g8; n < NPATCH; n += 8)
                acc += alpha_l[n] * keys[(size_t)(b * NPATCH + n) * 512 + d0 + dl];
            pbuf[g8][dl] = acc;
            __syncthreads();
            if (tid < 32) {
                float s = 0.f;
#pragma unroll
                for (int g = 0; g < 8; ++g) s += pbuf[g][tid];
                ctx[b * 512 + d0 + tid] = s * inv;
            }
        }
        grid_barrier(bar_cnt, bar_flag, gen);

        // ===== S4: gates (fp32 LDS weights) + LSTM cell for own d-pair =====
        for (int bp = 0; bp < 8; ++bp) {
            for (int idx = tid; idx < 3072; idx += 256) {
                int bb = (idx >= 1536) ? 1 : 0;
                int kz = idx - bb * 1536;
                int b = bp * 2 + bb;
                float v;
                if (kz < 512)       v = x_all[((size_t)b * T_STEPS + t) * 512 + kz];
                else if (kz < 1024) v = ctx[b * 512 + (kz - 512)];
                else                v = hln[b * 512 + (kz - 1024)];
                zbuf[bb][kz] = v;
            }
            __syncthreads();
            {
                int dot = tid >> 4, seg = tid & 15;
                int r = dot >> 1, bb = dot & 1;
                const float4* wr4 = (const float4*)&Wg[r][0];
                const float4* z4 = (const float4*)&zbuf[bb][0];
                float acc = 0.f;
#pragma unroll 6
                for (int i = 0; i < 24; ++i) {
                    int k4 = seg + i * 16;
                    float4 w4 = wr4[k4], zz = z4[k4];
                    acc += w4.x * zz.x + w4.y * zz.y + w4.z * zz.z + w4.w * zz.w;
                }
#pragma unroll
                for (int m = 1; m < 16; m <<= 1) acc += __shfl_xor(acc, m);
                if (seg == 0) gbuf[bb][r] = acc + bias8[r];
            }
            __syncthreads();
            if (tid < 4) {
                int bb = tid >> 1, dd = tid & 1;
                int b = bp * 2 + bb, d = 2 * k + dd;
                float iv = gbuf[bb][0 + dd], fv = gbuf[bb][2 + dd];
                float gv = gbuf[bb][4 + dd], ov = gbuf[bb][6 + dd];
                float cn = sigm(fv) * c_g[b * 512 + d] + sigm(iv) * ftanh(gv);
                c_g[b * 512 + d] = cn;
                float hr = sigm(ov) * ftanh(cn);
                h_raw[b * 512 + d] = hr;
                float s1 = hr, s2 = hr * hr;
                s1 += __shfl_xor(s1, 1); s2 += __shfl_xor(s2, 1);
                if (dd == 0) {
                    partials[((size_t)b * NB + k) * 2 + 0] = s1;
                    partials[((size_t)b * NB + k) * 2 + 1] = s2;
                }
            }
            __syncthreads();
        }
        grid_barrier(bar_cnt, bar_flag, gen);
    }

    // tail: final LN -> h_all row 127
    {
        int b = tid >> 4, i = tid & 15;
        float s1 = 0.f, s2 = 0.f;
        const float* pp = partials + ((size_t)b * NB + i * 16) * 2;
#pragma unroll 4
        for (int q = 0; q < 16; ++q) { s1 += pp[q * 2]; s2 += pp[q * 2 + 1]; }
#pragma unroll
        for (int m = 1; m < 16; m <<= 1) { s1 += __shfl_xor(s1, m); s2 += __shfl_xor(s2, m); }
        if (i == 0) {
            float muv = s1 * (1.f / 512.f);
            float varv = s2 * (1.f / 512.f) - muv * muv;
            mu_s[b] = muv; rr_s[b] = rsqrtf(varv + 1e-5f);
        }
        __syncthreads();
        if (tid < 32) {
            int b2 = tid >> 1, dd = tid & 1, d = 2 * k + dd;
            float hr = h_raw[b2 * 512 + d];
            float val = (hr - mu_s[b2]) * rr_s[b2] * lng[d] + lnb[d];
            h_all_b[((size_t)b2 * T_STEPS + (T_STEPS - 1)) * 512 + d] = f2b(val);
        }
    }
}

extern "C" void kernel_launch(void* const* d_in, const int* in_sizes, int n_in,
                              void* d_out, int out_size, void* d_ws, size_t ws_size,
                              hipStream_t stream)
{
    const float* patches = (const float*)d_in[0];
    const float* cls     = (const float*)d_in[1];
    const int*   tgt     = (const int*)d_in[2];
    const float* kv_w    = (const float*)d_in[3];
    const float* kv_b    = (const float*)d_in[4];
    const float* ih_w    = (const float*)d_in[5];
    const float* ih_b    = (const float*)d_in[6];
    const float* ic_w    = (const float*)d_in[7];
    const float* ic_b    = (const float*)d_in[8];
    const float* emb     = (const float*)d_in[9];
    const float* Wh      = (const float*)d_in[10];
    const float* Wk      = (const float*)d_in[11];
    const float* av      = (const float*)d_in[12];
    const float* Wih     = (const float*)d_in[13];
    const float* Whh     = (const float*)d_in[14];
    const float* bih     = (const float*)d_in[15];
    const float* bhh     = (const float*)d_in[16];
    const float* lng     = (const float*)d_in[17];
    const float* lnb     = (const float*)d_in[18];
    const float* outw    = (const float*)d_in[19];
    const float* outb    = (const float*)d_in[20];
    float* out = (float*)d_out;

    char* wsp = (char*)d_ws;
    auto carve = [&](size_t bytes) -> char* {
        char* p = wsp; wsp += (bytes + 255) & ~(size_t)255; return p;
    };
    float*          keys_f   = (float*)carve((size_t)3136 * 512 * 4);
    float*          keysWk_f = (float*)carve((size_t)3136 * 512 * 4);
    unsigned short* keysH    = (unsigned short*)carve((size_t)3136 * 512 * 2);
    unsigned short* keysL    = (unsigned short*)carve((size_t)3136 * 512 * 2);
    float*          x_all_f  = (float*)carve((size_t)2048 * 512 * 4);
    unsigned short* h_all_b  = (unsigned short*)carve((size_t)2048 * 512 * 2);
    unsigned short* kvwH     = (unsigned short*)carve((size_t)512 * 768 * 2);
    unsigned short* kvwL     = (unsigned short*)carve((size_t)512 * 768 * 2);
    unsigned short* wkH      = (unsigned short*)carve((size_t)512 * 512 * 2);
    unsigned short* wkL      = (unsigned short*)carve((size_t)512 * 512 * 2);
    unsigned short* outw_b   = (unsigned short*)carve((size_t)VOCAB * 512 * 2);  // 10.24 MB
    float* ctx      = (float*)carve((size_t)16 * 512 * 4);
    float* hln      = (float*)carve((size_t)16 * 512 * 4);
    float* h_raw    = (float*)carve((size_t)16 * 512 * 4);
    float* c_g      = (float*)carve((size_t)16 * 512 * 4);
    float* ew_g     = (float*)carve((size_t)16 * 512 * 4);
    float* sc_g     = (float*)carve((size_t)16 * NPATCH * 4);
    float* partials = (float*)carve((size_t)16 * NB * 2 * 4);
    int*   bar      = (int*)carve(512);   // cnt at byte 0, flag at byte 256 — BOTH inside memset
    // patches split (4.82+4.82 MB) aliases outw_b; outw converted after keys GEMM.
    unsigned short* patH = outw_b;
    unsigned short* patL = outw_b + (size_t)3136 * 768;

    // zero the ENTIRE barrier state every call (flag too!) — graph replays re-run this.
    hipMemsetAsync(bar, 0, 512, stream);

    auto cvt = [&](const float* s, unsigned short* d, int n) {
        cvt_kernel<<<(n / 8 + 255) / 256, 256, 0, stream>>>(s, d, n);
    };
    auto cvts = [&](const float* s, unsigned short* dh, unsigned short* dl, int n) {
        cvt_split_kernel<<<(n / 8 + 255) / 256, 256, 0, stream>>>(s, dh, dl, n);
    };
    cvts(patches, patH, patL, 3136 * 768);
    cvts(kv_w, kvwH, kvwL, 512 * 768);
    cvts(Wk, wkH, wkL, 512 * 512);

    // keys = patches @ kv_w^T + kv_b : fp32 + split-bf16 outputs
    gemm_mfma<<<dim3(25, 4), 256, 0, stream>>>(patH, patL, kvwH, kvwL, kv_b,
                                               keys_f, keysH, keysL, 3136, 512, 768);
    // patches region free now: convert outw into it
    cvt(outw, outw_b, VOCAB * 512);
    // keysWk = keys @ Wk^T : fp32 out
    gemm_mfma<<<dim3(25, 4), 256, 0, stream>>>(keysH, keysL, wkH, wkL, nullptr,
                                               keysWk_f, nullptr, nullptr, 3136, 512, 512);

    h0c0_kernel<<<64, 256, 0, stream>>>(cls, ih_w, ih_b, ic_w, ic_b, c_g, h_raw, hln);
    gather_kernel<<<1024, 256, 0, stream>>>(tgt, emb, x_all_f);

    // persistent recurrence: all 128 steps in one launch (grid = 256 = #CUs, 64KB LDS -> resident)
    recur_kernel<<<NB, 256, 0, stream>>>(x_all_f, ctx, hln, h_raw, c_g, ew_g, sc_g, partials,
                                         keys_f, keysWk_f, Wih, Whh, bih, bhh, Wh,
                                         lng, lnb, av, h_all_b, bar, bar + 64);

    // logits = h_all @ outw^T + out_b  (bf16 MFMA, fp32 out)
    gemm_mfma<<<dim3(16, 79), 256, 0, stream>>>(h_all_b, nullptr, outw_b, nullptr, outb,
                                                out, nullptr, nullptr, 2048, VOCAB, 512);
}

// Round 8
// 12856.358 us; speedup vs baseline: 1.1063x; 1.1063x over previous
//
#include <hip/hip_runtime.h>
#include <hip/hip_bf16.h>

#define T_STEPS 128
#define DH      512
#define NPATCH  196
#define BATCH   16
#define VOCAB   10000
#define NB2     64     // persistent grid: 64 blocks x 1024 threads
#define EWI(d)  ((d) + ((d) >> 6))   // skewed LDS index: breaks 64-stride bank aliasing

typedef __attribute__((ext_vector_type(8))) short bf16x8;
typedef __attribute__((ext_vector_type(4))) float f32x4;

__device__ __forceinline__ float sigm(float x) { return 1.0f / (1.0f + __expf(-x)); }
__device__ __forceinline__ float ftanh(float x) {
    float e = __expf(2.0f * x);
    return 1.0f - 2.0f / (e + 1.0f);
}
__device__ __forceinline__ unsigned short f2b(float x) {
    union { float f; unsigned u; } v; v.f = x;
    unsigned r = (v.u + 0x7FFFu + ((v.u >> 16) & 1u)) >> 16;
    return (unsigned short)r;
}
__device__ __forceinline__ float b2f(unsigned short h) {
    union { unsigned u; float f; } v; v.u = ((unsigned)h) << 16;
    return v.f;
}

// ---------------- conversion kernels ----------------
__global__ __launch_bounds__(256)
void cvt_kernel(const float* __restrict__ src, unsigned short* __restrict__ dst, int n)
{
    int i = (blockIdx.x * 256 + threadIdx.x) * 8;
    if (i >= n) return;
    float4 v0 = *(const float4*)(src + i);
    float4 v1 = *(const float4*)(src + i + 4);
    float xs[8] = {v0.x, v0.y, v0.z, v0.w, v1.x, v1.y, v1.z, v1.w};
    bf16x8 o;
#pragma unroll
    for (int j = 0; j < 8; ++j) o[j] = (short)f2b(xs[j]);
    *(bf16x8*)(dst + i) = o;
}

__global__ __launch_bounds__(256)
void cvt_split_kernel(const float* __restrict__ src, unsigned short* __restrict__ hi,
                      unsigned short* __restrict__ lo, int n)
{
    int i = (blockIdx.x * 256 + threadIdx.x) * 8;
    if (i >= n) return;
    float4 v0 = *(const float4*)(src + i);
    float4 v1 = *(const float4*)(src + i + 4);
    float xs[8] = {v0.x, v0.y, v0.z, v0.w, v1.x, v1.y, v1.z, v1.w};
    bf16x8 h_, l_;
#pragma unroll
    for (int j = 0; j < 8; ++j) {
        unsigned short hb = f2b(xs[j]);
        float r = xs[j] - b2f(hb);
        h_[j] = (short)hb;
        l_[j] = (short)f2b(r);
    }
    *(bf16x8*)(hi + i) = h_;
    *(bf16x8*)(lo + i) = l_;
}

// ---------------- MFMA GEMM (3-term split; verified round 4) ----------------
__global__ __launch_bounds__(256)
void gemm_mfma(const unsigned short* __restrict__ AH, const unsigned short* __restrict__ AL,
               const unsigned short* __restrict__ WH, const unsigned short* __restrict__ WL,
               const float* __restrict__ bias, float* __restrict__ C,
               unsigned short* __restrict__ CbH, unsigned short* __restrict__ CbL,
               int M, int N, int K)
{
    const int tid = threadIdx.x, wid = tid >> 6, l = tid & 63;
    const int m0 = blockIdx.x * 128 + (wid >> 1) * 64;
    const int n0 = blockIdx.y * 128 + (wid & 1) * 64;
    const int lm = l & 15, lk = (l >> 4) * 8;
    f32x4 acc[4][4];
#pragma unroll
    for (int i = 0; i < 4; ++i)
#pragma unroll
        for (int j = 0; j < 4; ++j) acc[i][j] = (f32x4){0.f, 0.f, 0.f, 0.f};
    const bf16x8 az = {0,0,0,0,0,0,0,0};

    for (int k0 = 0; k0 < K; k0 += 32) {
        bf16x8 aH[4], aL[4];
#pragma unroll
        for (int mi = 0; mi < 4; ++mi) {
            int m = m0 + mi * 16 + lm;
            aH[mi] = (m < M) ? *(const bf16x8*)(AH + (size_t)m * K + k0 + lk) : az;
            aL[mi] = (AL && m < M) ? *(const bf16x8*)(AL + (size_t)m * K + k0 + lk) : az;
        }
#pragma unroll
        for (int ni = 0; ni < 4; ++ni) {
            int n = n0 + ni * 16 + lm;
            bf16x8 bH = az, bL = az;
            if (n < N) {
                bH = *(const bf16x8*)(WH + (size_t)n * K + k0 + lk);
                if (WL) bL = *(const bf16x8*)(WL + (size_t)n * K + k0 + lk);
            }
#pragma unroll
            for (int mi = 0; mi < 4; ++mi) {
                acc[mi][ni] = __builtin_amdgcn_mfma_f32_16x16x32_bf16(aH[mi], bH, acc[mi][ni], 0, 0, 0);
                if (WL) acc[mi][ni] = __builtin_amdgcn_mfma_f32_16x16x32_bf16(aH[mi], bL, acc[mi][ni], 0, 0, 0);
                if (AL) acc[mi][ni] = __builtin_amdgcn_mfma_f32_16x16x32_bf16(aL[mi], bH, acc[mi][ni], 0, 0, 0);
            }
        }
    }
    const int rr = (l >> 4) * 4;
#pragma unroll
    for (int mi = 0; mi < 4; ++mi) {
        int mb = m0 + mi * 16 + rr;
#pragma unroll
        for (int ni = 0; ni < 4; ++ni) {
            int n = n0 + ni * 16 + lm;
            if (n < N) {
                float bs = bias ? bias[n] : 0.f;
#pragma unroll
                for (int r = 0; r < 4; ++r) {
                    int mm = mb + r;
                    if (mm < M) {
                        float v = acc[mi][ni][r] + bs;
                        if (C)   C[(size_t)mm * N + n] = v;
                        if (CbH) {
                            unsigned short hb = f2b(v);
                            CbH[(size_t)mm * N + n] = hb;
                            if (CbL) CbL[(size_t)mm * N + n] = f2b(v - b2f(hb));
                        }
                    }
                }
            }
        }
    }
}

// ---------------- h0 / c0 (fp32) ----------------
__global__ __launch_bounds__(256)
void h0c0_kernel(const float* __restrict__ cls,
                 const float* __restrict__ ihw, const float* __restrict__ ihb,
                 const float* __restrict__ icw, const float* __restrict__ icb,
                 float* __restrict__ c_g, float* __restrict__ h_raw0)
{
    int id = blockIdx.x * 256 + threadIdx.x;   // 0..16383
    int which = id >> 13;
    int b = (id >> 9) & 15;
    int d = id & 511;
    const float* w = (which ? icw : ihw) + d * 768;
    const float* x = cls + b * 768;
    float acc = which ? icb[d] : ihb[d];
    const float4* x4 = (const float4*)x;
    const float4* w4 = (const float4*)w;
#pragma unroll 4
    for (int k = 0; k < 192; ++k) {
        float4 a = x4[k], ww = w4[k];
        acc += a.x * ww.x + a.y * ww.y + a.z * ww.z + a.w * ww.w;
    }
    if (which) c_g[b * 512 + d] = acc;
    else h_raw0[b * 512 + d] = acc;
}

// ---------------- embedding gather (fp32) ----------------
__global__ __launch_bounds__(256)
void gather_kernel(const int* __restrict__ ids, const float* __restrict__ emb,
                   float* __restrict__ x_all)
{
    int q = blockIdx.x * 256 + threadIdx.x;    // 2048 rows * 128 float4
    if (q >= 2048 * 128) return;
    int r = q >> 7, kq = q & 127;
    int tgt = ids[r];
    ((float4*)x_all)[(size_t)r * 128 + kq] = ((const float4*)emb)[(size_t)tgt * 128 + kq];
}

// ---------------- grid barrier: monotonic counter, relaxed poll, acquire on exit ----
// cnt zeroed by 512B memset each call (replay-safe: no reset-race, count only grows).
__device__ __forceinline__ void gbar(int* cnt, int target)
{
    __syncthreads();
    if (threadIdx.x == 0) {
        __hip_atomic_fetch_add(cnt, 1, __ATOMIC_ACQ_REL, __HIP_MEMORY_SCOPE_AGENT);
        while (__hip_atomic_load(cnt, __ATOMIC_RELAXED, __HIP_MEMORY_SCOPE_AGENT) < target)
            __builtin_amdgcn_s_sleep(1);
        (void)__hip_atomic_load(cnt, __ATOMIC_ACQUIRE, __HIP_MEMORY_SCOPE_AGENT);
    }
    __syncthreads();
}

// ---------------- persistent recurrence: 64 blocks x 1024 threads, 2 barriers/step ----
// Block k: batch-owner b_own=k>>2 + ctx quarter q=k&3 (Phase B);
//          gate-rows j = g*512 + 8k + dd (g=0..3, dd=0..7) i.e. d in [8k,8k+8) (Phase C).
// Gate weights: 48 fp32 per thread in REGISTERS, element k = seg + 32*i (conflict-free
// LDS z reads, coalesced one-time global load). h_raw/partials double-buffered (parity t).
__global__ __launch_bounds__(1024, 4)
void recur2_kernel(const float* __restrict__ x_all, float* __restrict__ ctx,
                   float* __restrict__ h_raw2, float* __restrict__ c_g,
                   float* __restrict__ partials2,
                   const float* __restrict__ keys, const float* __restrict__ keysWk,
                   const float* __restrict__ Wih, const float* __restrict__ Whh,
                   const float* __restrict__ bih, const float* __restrict__ bhh,
                   const float* __restrict__ Wh, const float* __restrict__ lng,
                   const float* __restrict__ lnb, const float* __restrict__ vvec,
                   unsigned short* __restrict__ h_all_b, int* __restrict__ cnt)
{
    __shared__ float zs[8][1536];            // 48KB: z=[x|ctx|hln] for 8 batches/pass
    __shared__ float hv[512];                // B': LN'd h of b_own
    __shared__ float ew[520];                // skewed (EWI)
    __shared__ float vv[520];                // skewed (EWI)
    __shared__ float sc[200], al[200];
    __shared__ float pb[8][128];
    __shared__ float gbuf[16][32];
    __shared__ float mu_s[16], rr_s[16], bias_l[32], red[32];

    const int k = blockIdx.x, tid = threadIdx.x;
    const int b_own = k >> 2, q = k & 3;
    const int rr = tid >> 5, seg = tid & 31;

    // one-time: gate-weight registers, bias, vvec
    float wreg[48];
    {
        int g = rr >> 3, dd = rr & 7;
        int j = g * 512 + 8 * k + dd;
        const float* wih_row = Wih + (size_t)j * 1024;
        const float* whh_row = Whh + (size_t)j * 512;
#pragma unroll
        for (int i = 0; i < 48; ++i) {
            int kk = seg + 32 * i;
            wreg[i] = (kk < 1024) ? wih_row[kk] : whh_row[kk - 1024];
        }
        if (tid < 32) {
            int g2 = tid >> 3, dd2 = tid & 7, j2 = g2 * 512 + 8 * k + dd2;
            bias_l[tid] = bih[j2] + bhh[j2];
        }
        if (tid < 512) vv[EWI(tid)] = vvec[tid];
    }
    __syncthreads();

    int bargen = 0;
    for (int t = 0; t < T_STEPS; ++t) {
        const float* hcur = h_raw2 + (t & 1) * (BATCH * 512);
        float* hnxt = h_raw2 + ((t + 1) & 1) * (BATCH * 512);
        const float* pcur = partials2 + (t & 1) * (BATCH * 64 * 2);
        float* pnxt = partials2 + ((t + 1) & 1) * (BATCH * 64 * 2);

        // ======== Phase B: LN stats(b_own) + ew(full) + scores + softmax + ctx slice ====
        if (t > 0) {
            if (tid < 64) {
                const float* pp = pcur + ((size_t)b_own * 64 + tid) * 2;
                float s1 = pp[0], s2 = pp[1];
#pragma unroll
                for (int m = 1; m < 64; m <<= 1) { s1 += __shfl_xor(s1, m); s2 += __shfl_xor(s2, m); }
                if (tid == 0) {
                    float mu = s1 * (1.f / 512.f);
                    float var = s2 * (1.f / 512.f) - mu * mu;
                    red[0] = mu; red[1] = rsqrtf(var + 1e-5f);
                }
            }
        } else if (tid == 0) { red[0] = 0.f; red[1] = 1.f; }
        __syncthreads();
        {
            float mu_b = red[0], rr_b = red[1];
            if (tid < 128) {
                float4 h4 = ((const float4*)(hcur + b_own * 512))[tid];
                if (t > 0) {
                    float4 g4 = ((const float4*)lng)[tid], bl4 = ((const float4*)lnb)[tid];
                    h4.x = (h4.x - mu_b) * rr_b * g4.x + bl4.x;
                    h4.y = (h4.y - mu_b) * rr_b * g4.y + bl4.y;
                    h4.z = (h4.z - mu_b) * rr_b * g4.z + bl4.z;
                    h4.w = (h4.w - mu_b) * rr_b * g4.w + bl4.w;
                }
                ((float4*)hv)[tid] = h4;
            }
        }
        __syncthreads();
        {   // ew[e] = hv . Wh[e,:], 2 threads per e
            int e = tid >> 1, half = tid & 1;
            const float4* wr4 = (const float4*)(Wh + (size_t)e * 512) + half * 64;
            const float4* hh4 = (const float4*)hv + half * 64;
            float s = 0.f;
#pragma unroll 8
            for (int i = 0; i < 64; ++i) {
                float4 w4 = wr4[i], h4 = hh4[i];
                s += w4.x * h4.x + w4.y * h4.y + w4.z * h4.z + w4.w * h4.w;
            }
            s += __shfl_xor(s, 1);
            if (half == 0) ew[EWI(e)] = s;
        }
        __syncthreads();
        {   // scores[n] = sum_d tanh(ew+kw)*v ; 8 threads per n, 2 passes
#pragma unroll
            for (int pass = 0; pass < 2; ++pass) {
                int n = pass * 128 + (tid >> 3);
                if (n < NPATCH) {
                    int s8 = tid & 7;
                    const float4* kw4 = (const float4*)(keysWk + ((size_t)(b_own * NPATCH + n)) * 512) + s8 * 16;
                    float s = 0.f;
#pragma unroll
                    for (int i = 0; i < 16; ++i) {
                        float4 kk = kw4[i];
                        int d0 = s8 * 64 + i * 4;
                        s += ftanh(ew[EWI(d0 + 0)] + kk.x) * vv[EWI(d0 + 0)]
                           + ftanh(ew[EWI(d0 + 1)] + kk.y) * vv[EWI(d0 + 1)]
                           + ftanh(ew[EWI(d0 + 2)] + kk.z) * vv[EWI(d0 + 2)]
                           + ftanh(ew[EWI(d0 + 3)] + kk.w) * vv[EWI(d0 + 3)];
                    }
#pragma unroll
                    for (int m = 1; m < 8; m <<= 1) s += __shfl_xor(s, m);
                    if (s8 == 0) sc[n] = s;
                }
            }
        }
        __syncthreads();
        // softmax over 196 (threads < 256 carry values)
        float sv = (tid < NPATCH) ? sc[tid] : -1e30f;
        {
            float m1 = sv;
#pragma unroll
            for (int m = 1; m < 64; m <<= 1) m1 = fmaxf(m1, __shfl_xor(m1, m));
            if ((tid & 63) == 0 && tid < 256) red[8 + (tid >> 6)] = m1;
        }
        __syncthreads();
        {
            float mx = fmaxf(fmaxf(red[8], red[9]), fmaxf(red[10], red[11]));
            float ev = (tid < NPATCH) ? __expf(sv - mx) : 0.f;
            if (tid < NPATCH) al[tid] = ev;
            float s2 = ev;
#pragma unroll
            for (int m = 1; m < 64; m <<= 1) s2 += __shfl_xor(s2, m);
            if ((tid & 63) == 0 && tid < 256) red[12 + (tid >> 6)] = s2;
        }
        __syncthreads();
        {   // ctx q-slice: 128 d's, 8 n-groups
            float inv = 1.f / (red[12] + red[13] + red[14] + red[15]);
            int d_loc = tid & 127, g8 = tid >> 7;
            const float* kb = keys + (size_t)(b_own * NPATCH) * 512 + q * 128 + d_loc;
            float acc = 0.f;
            for (int n = g8; n < NPATCH; n += 8) acc += al[n] * kb[(size_t)n * 512];
            pb[g8][d_loc] = acc;
            __syncthreads();
            if (tid < 128) {
                float s = 0.f;
#pragma unroll
                for (int g = 0; g < 8; ++g) s += pb[g][tid];
                ctx[b_own * 512 + q * 128 + tid] = s * inv;
            }
        }
        gbar(cnt, ++bargen * NB2);

        // ======== Phase C: stats(all b) + z-stage(+h_all) + gates + cell ========
        if (t > 0) {
            int bb = tid >> 6, i = tid & 63;
            const float* pp = pcur + ((size_t)bb * 64 + i) * 2;
            float s1 = pp[0], s2 = pp[1];
#pragma unroll
            for (int m = 1; m < 64; m <<= 1) { s1 += __shfl_xor(s1, m); s2 += __shfl_xor(s2, m); }
            if (i == 0) {
                float mu = s1 * (1.f / 512.f);
                float var = s2 * (1.f / 512.f) - mu * mu;
                mu_s[bb] = mu; rr_s[bb] = rsqrtf(var + 1e-5f);
            }
        } else if (tid < 16) { mu_s[tid] = 0.f; rr_s[tid] = 1.f; }
        __syncthreads();

#pragma unroll
        for (int p = 0; p < 2; ++p) {
            {   // stage 8 batches: x | ctx | hln (hln computed inline; also write h_all row t-1)
                int bb = tid >> 7, kq = tid & 127;
                int b = p * 8 + bb;
                ((float4*)&zs[bb][0])[kq]   = ((const float4*)(x_all + ((size_t)b * T_STEPS + t) * 512))[kq];
                ((float4*)&zs[bb][512])[kq] = ((const float4*)(ctx + b * 512))[kq];
                float4 h4 = ((const float4*)(hcur + b * 512))[kq];
                if (t > 0) {
                    float mu = mu_s[b], rv = rr_s[b];
                    float4 g4 = ((const float4*)lng)[kq], bl4 = ((const float4*)lnb)[kq];
                    h4.x = (h4.x - mu) * rv * g4.x + bl4.x;
                    h4.y = (h4.y - mu) * rv * g4.y + bl4.y;
                    h4.z = (h4.z - mu) * rv * g4.z + bl4.z;
                    h4.w = (h4.w - mu) * rv * g4.w + bl4.w;
                    short4 hb = { (short)f2b(h4.x), (short)f2b(h4.y), (short)f2b(h4.z), (short)f2b(h4.w) };
                    *(short4*)(h_all_b + ((size_t)b * T_STEPS + (t - 1)) * 512 + kq * 4) = hb;
                }
                ((float4*)&zs[bb][1024])[kq] = h4;
            }
            __syncthreads();
            {   // gates: register weights x LDS z (bank-conflict-free: element seg+32i)
#pragma unroll
                for (int bl = 0; bl < 8; ++bl) {
                    float acc = 0.f;
#pragma unroll
                    for (int i = 0; i < 48; ++i) acc += wreg[i] * zs[bl][seg + 32 * i];
#pragma unroll
                    for (int m = 1; m < 32; m <<= 1) acc += __shfl_xor(acc, m);
                    if (seg == 0) gbuf[p * 8 + bl][rr] = acc;
                }
            }
            __syncthreads();
        }
        {   // cell for own 8 d's x 16 batches
            if (tid < 128) {
                int bp = tid >> 3, dd = tid & 7, d = 8 * k + dd;
                float gi = gbuf[bp][dd]      + bias_l[dd];
                float gf = gbuf[bp][8 + dd]  + bias_l[8 + dd];
                float gg = gbuf[bp][16 + dd] + bias_l[16 + dd];
                float go = gbuf[bp][24 + dd] + bias_l[24 + dd];
                float cn = sigm(gf) * c_g[bp * 512 + d] + sigm(gi) * ftanh(gg);
                c_g[bp * 512 + d] = cn;
                float hr = sigm(go) * ftanh(cn);
                hnxt[bp * 512 + d] = hr;
                float s1 = hr, s2 = hr * hr;
#pragma unroll
                for (int m = 1; m < 8; m <<= 1) { s1 += __shfl_xor(s1, m); s2 += __shfl_xor(s2, m); }
                if (dd == 0) {
                    pnxt[((size_t)bp * 64 + k) * 2 + 0] = s1;
                    pnxt[((size_t)bp * 64 + k) * 2 + 1] = s2;
                }
            }
        }
        gbar(cnt, ++bargen * NB2);
    }

    // tail: h_all row 127 = LN(h_raw) ; blocks 0..15 handle batch b = k
    if (k < 16) {
        const float* hcur = h_raw2 + ((T_STEPS & 1)) * (BATCH * 512);
        const float* pcur = partials2 + ((T_STEPS & 1)) * (BATCH * 64 * 2);
        int b = k;
        if (tid < 64) {
            const float* pp = pcur + ((size_t)b * 64 + tid) * 2;
            float s1 = pp[0], s2 = pp[1];
#pragma unroll
            for (int m = 1; m < 64; m <<= 1) { s1 += __shfl_xor(s1, m); s2 += __shfl_xor(s2, m); }
            if (tid == 0) {
                float mu = s1 * (1.f / 512.f);
                float var = s2 * (1.f / 512.f) - mu * mu;
                red[0] = mu; red[1] = rsqrtf(var + 1e-5f);
            }
        }
        __syncthreads();
        if (tid < 128) {
            float mu = red[0], rv = red[1];
            float4 h4 = ((const float4*)(hcur + b * 512))[tid];
            float4 g4 = ((const float4*)lng)[tid], bl4 = ((const float4*)lnb)[tid];
            h4.x = (h4.x - mu) * rv * g4.x + bl4.x;
            h4.y = (h4.y - mu) * rv * g4.y + bl4.y;
            h4.z = (h4.z - mu) * rv * g4.z + bl4.z;
            h4.w = (h4.w - mu) * rv * g4.w + bl4.w;
            short4 hb = { (short)f2b(h4.x), (short)f2b(h4.y), (short)f2b(h4.z), (short)f2b(h4.w) };
            *(short4*)(h_all_b + ((size_t)b * T_STEPS + (T_STEPS - 1)) * 512 + tid * 4) = hb;
        }
    }
}

extern "C" void kernel_launch(void* const* d_in, const int* in_sizes, int n_in,
                              void* d_out, int out_size, void* d_ws, size_t ws_size,
                              hipStream_t stream)
{
    const float* patches = (const float*)d_in[0];
    const float* cls     = (const float*)d_in[1];
    const int*   tgt     = (const int*)d_in[2];
    const float* kv_w    = (const float*)d_in[3];
    const float* kv_b    = (const float*)d_in[4];
    const float* ih_w    = (const float*)d_in[5];
    const float* ih_b    = (const float*)d_in[6];
    const float* ic_w    = (const float*)d_in[7];
    const float* ic_b    = (const float*)d_in[8];
    const float* emb     = (const float*)d_in[9];
    const float* Wh      = (const float*)d_in[10];
    const float* Wk      = (const float*)d_in[11];
    const float* av      = (const float*)d_in[12];
    const float* Wih     = (const float*)d_in[13];
    const float* Whh     = (const float*)d_in[14];
    const float* bih     = (const float*)d_in[15];
    const float* bhh     = (const float*)d_in[16];
    const float* lng     = (const float*)d_in[17];
    const float* lnb     = (const float*)d_in[18];
    const float* outw    = (const float*)d_in[19];
    const float* outb    = (const float*)d_in[20];
    float* out = (float*)d_out;

    char* wsp = (char*)d_ws;
    auto carve = [&](size_t bytes) -> char* {
        char* p = wsp; wsp += (bytes + 255) & ~(size_t)255; return p;
    };
    float*          keys_f   = (float*)carve((size_t)3136 * 512 * 4);
    float*          keysWk_f = (float*)carve((size_t)3136 * 512 * 4);
    unsigned short* keysH    = (unsigned short*)carve((size_t)3136 * 512 * 2);
    unsigned short* keysL    = (unsigned short*)carve((size_t)3136 * 512 * 2);
    float*          x_all_f  = (float*)carve((size_t)2048 * 512 * 4);
    unsigned short* h_all_b  = (unsigned short*)carve((size_t)2048 * 512 * 2);
    unsigned short* kvwH     = (unsigned short*)carve((size_t)512 * 768 * 2);
    unsigned short* kvwL     = (unsigned short*)carve((size_t)512 * 768 * 2);
    unsigned short* wkH      = (unsigned short*)carve((size_t)512 * 512 * 2);
    unsigned short* wkL      = (unsigned short*)carve((size_t)512 * 512 * 2);
    unsigned short* outw_b   = (unsigned short*)carve((size_t)VOCAB * 512 * 2);  // 10.24 MB
    float* ctx      = (float*)carve((size_t)16 * 512 * 4);
    float* h_raw2   = (float*)carve((size_t)2 * 16 * 512 * 4);
    float* c_g      = (float*)carve((size_t)16 * 512 * 4);
    float* partials2= (float*)carve((size_t)2 * 16 * 64 * 2 * 4);
    int*   bar      = (int*)carve(512);
    // patches split aliases outw_b; outw converted after keys GEMM.
    unsigned short* patH = outw_b;
    unsigned short* patL = outw_b + (size_t)3136 * 768;

    hipMemsetAsync(bar, 0, 512, stream);

    auto cvt = [&](const float* s, unsigned short* d, int n) {
        cvt_kernel<<<(n / 8 + 255) / 256, 256, 0, stream>>>(s, d, n);
    };
    auto cvts = [&](const float* s, unsigned short* dh, unsigned short* dl, int n) {
        cvt_split_kernel<<<(n / 8 + 255) / 256, 256, 0, stream>>>(s, dh, dl, n);
    };
    cvts(patches, patH, patL, 3136 * 768);
    cvts(kv_w, kvwH, kvwL, 512 * 768);
    cvts(Wk, wkH, wkL, 512 * 512);

    // keys = patches @ kv_w^T + kv_b : fp32 + split-bf16 outputs
    gemm_mfma<<<dim3(25, 4), 256, 0, stream>>>(patH, patL, kvwH, kvwL, kv_b,
                                               keys_f, keysH, keysL, 3136, 512, 768);
    // patches region free now: convert outw into it
    cvt(outw, outw_b, VOCAB * 512);
    // keysWk = keys @ Wk^T : fp32 out
    gemm_mfma<<<dim3(25, 4), 256, 0, stream>>>(keysH, keysL, wkH, wkL, nullptr,
                                               keysWk_f, nullptr, nullptr, 3136, 512, 512);

    h0c0_kernel<<<64, 256, 0, stream>>>(cls, ih_w, ih_b, ic_w, ic_b, c_g, h_raw2);
    gather_kernel<<<1024, 256, 0, stream>>>(tgt, emb, x_all_f);

    // persistent recurrence: 64 blocks x 1024 threads, 2 grid barriers per step
    recur2_kernel<<<NB2, 1024, 0, stream>>>(x_all_f, ctx, h_raw2, c_g, partials2,
                                            keys_f, keysWk_f, Wih, Whh, bih, bhh, Wh,
                                            lng, lnb, av, h_all_b, bar);

    // logits = h_all @ outw^T + out_b  (bf16 MFMA, fp32 out)
    gemm_mfma<<<dim3(16, 79), 256, 0, stream>>>(h_all_b, nullptr, outw_b, nullptr, outb,
                                                out, nullptr, nullptr, 2048, VOCAB, 512);
}

// Round 9
// 12475.838 us; speedup vs baseline: 1.1401x; 1.0305x over previous
//
#include <hip/hip_runtime.h>
#include <hip/hip_bf16.h>

#define T_STEPS 128
#define DH      512
#define NPATCH  196
#define BATCH   16
#define VOCAB   10000
#define NB3     64     // persistent grid: 64 blocks x 1024 threads

typedef __attribute__((ext_vector_type(8))) short bf16x8;
typedef __attribute__((ext_vector_type(4))) float f32x4;

__device__ __forceinline__ float sigm(float x) { return 1.0f / (1.0f + __expf(-x)); }
__device__ __forceinline__ float ftanh(float x) {
    float e = __expf(2.0f * x);
    return 1.0f - 2.0f / (e + 1.0f);
}
__device__ __forceinline__ unsigned short f2b(float x) {
    union { float f; unsigned u; } v; v.f = x;
    unsigned r = (v.u + 0x7FFFu + ((v.u >> 16) & 1u)) >> 16;
    return (unsigned short)r;
}
__device__ __forceinline__ float b2f(unsigned short h) {
    union { unsigned u; float f; } v; v.u = ((unsigned)h) << 16;
    return v.f;
}

// ---------------- conversion kernels ----------------
__global__ __launch_bounds__(256)
void cvt_kernel(const float* __restrict__ src, unsigned short* __restrict__ dst, int n)
{
    int i = (blockIdx.x * 256 + threadIdx.x) * 8;
    if (i >= n) return;
    float4 v0 = *(const float4*)(src + i);
    float4 v1 = *(const float4*)(src + i + 4);
    float xs[8] = {v0.x, v0.y, v0.z, v0.w, v1.x, v1.y, v1.z, v1.w};
    bf16x8 o;
#pragma unroll
    for (int j = 0; j < 8; ++j) o[j] = (short)f2b(xs[j]);
    *(bf16x8*)(dst + i) = o;
}

__global__ __launch_bounds__(256)
void cvt_split_kernel(const float* __restrict__ src, unsigned short* __restrict__ hi,
                      unsigned short* __restrict__ lo, int n)
{
    int i = (blockIdx.x * 256 + threadIdx.x) * 8;
    if (i >= n) return;
    float4 v0 = *(const float4*)(src + i);
    float4 v1 = *(const float4*)(src + i + 4);
    float xs[8] = {v0.x, v0.y, v0.z, v0.w, v1.x, v1.y, v1.z, v1.w};
    bf16x8 h_, l_;
#pragma unroll
    for (int j = 0; j < 8; ++j) {
        unsigned short hb = f2b(xs[j]);
        float r = xs[j] - b2f(hb);
        h_[j] = (short)hb;
        l_[j] = (short)f2b(r);
    }
    *(bf16x8*)(hi + i) = h_;
    *(bf16x8*)(lo + i) = l_;
}

// ---------------- MFMA GEMM (3-term split; verified round 4) ----------------
__global__ __launch_bounds__(256)
void gemm_mfma(const unsigned short* __restrict__ AH, const unsigned short* __restrict__ AL,
               const unsigned short* __restrict__ WH, const unsigned short* __restrict__ WL,
               const float* __restrict__ bias, float* __restrict__ C,
               unsigned short* __restrict__ CbH, unsigned short* __restrict__ CbL,
               int M, int N, int K)
{
    const int tid = threadIdx.x, wid = tid >> 6, l = tid & 63;
    const int m0 = blockIdx.x * 128 + (wid >> 1) * 64;
    const int n0 = blockIdx.y * 128 + (wid & 1) * 64;
    const int lm = l & 15, lk = (l >> 4) * 8;
    f32x4 acc[4][4];
#pragma unroll
    for (int i = 0; i < 4; ++i)
#pragma unroll
        for (int j = 0; j < 4; ++j) acc[i][j] = (f32x4){0.f, 0.f, 0.f, 0.f};
    const bf16x8 az = {0,0,0,0,0,0,0,0};

    for (int k0 = 0; k0 < K; k0 += 32) {
        bf16x8 aH[4], aL[4];
#pragma unroll
        for (int mi = 0; mi < 4; ++mi) {
            int m = m0 + mi * 16 + lm;
            aH[mi] = (m < M) ? *(const bf16x8*)(AH + (size_t)m * K + k0 + lk) : az;
            aL[mi] = (AL && m < M) ? *(const bf16x8*)(AL + (size_t)m * K + k0 + lk) : az;
        }
#pragma unroll
        for (int ni = 0; ni < 4; ++ni) {
            int n = n0 + ni * 16 + lm;
            bf16x8 bH = az, bL = az;
            if (n < N) {
                bH = *(const bf16x8*)(WH + (size_t)n * K + k0 + lk);
                if (WL) bL = *(const bf16x8*)(WL + (size_t)n * K + k0 + lk);
            }
#pragma unroll
            for (int mi = 0; mi < 4; ++mi) {
                acc[mi][ni] = __builtin_amdgcn_mfma_f32_16x16x32_bf16(aH[mi], bH, acc[mi][ni], 0, 0, 0);
                if (WL) acc[mi][ni] = __builtin_amdgcn_mfma_f32_16x16x32_bf16(aH[mi], bL, acc[mi][ni], 0, 0, 0);
                if (AL) acc[mi][ni] = __builtin_amdgcn_mfma_f32_16x16x32_bf16(aL[mi], bH, acc[mi][ni], 0, 0, 0);
            }
        }
    }
    const int rr = (l >> 4) * 4;
#pragma unroll
    for (int mi = 0; mi < 4; ++mi) {
        int mb = m0 + mi * 16 + rr;
#pragma unroll
        for (int ni = 0; ni < 4; ++ni) {
            int n = n0 + ni * 16 + lm;
            if (n < N) {
                float bs = bias ? bias[n] : 0.f;
#pragma unroll
                for (int r = 0; r < 4; ++r) {
                    int mm = mb + r;
                    if (mm < M) {
                        float v = acc[mi][ni][r] + bs;
                        if (C)   C[(size_t)mm * N + n] = v;
                        if (CbH) {
                            unsigned short hb = f2b(v);
                            CbH[(size_t)mm * N + n] = hb;
                            if (CbL) CbL[(size_t)mm * N + n] = f2b(v - b2f(hb));
                        }
                    }
                }
            }
        }
    }
}

// ---------------- h0 / c0 (fp32) ----------------
__global__ __launch_bounds__(256)
void h0c0_kernel(const float* __restrict__ cls,
                 const float* __restrict__ ihw, const float* __restrict__ ihb,
                 const float* __restrict__ icw, const float* __restrict__ icb,
                 float* __restrict__ c_g, float* __restrict__ h_raw0)
{
    int id = blockIdx.x * 256 + threadIdx.x;   // 0..16383
    int which = id >> 13;
    int b = (id >> 9) & 15;
    int d = id & 511;
    const float* w = (which ? icw : ihw) + d * 768;
    const float* x = cls + b * 768;
    float acc = which ? icb[d] : ihb[d];
    const float4* x4 = (const float4*)x;
    const float4* w4 = (const float4*)w;
#pragma unroll 4
    for (int k = 0; k < 192; ++k) {
        float4 a = x4[k], ww = w4[k];
        acc += a.x * ww.x + a.y * ww.y + a.z * ww.z + a.w * ww.w;
    }
    if (which) c_g[b * 512 + d] = acc;
    else h_raw0[b * 512 + d] = acc;
}

// ---------------- embedding gather (fp32) ----------------
__global__ __launch_bounds__(256)
void gather_kernel(const int* __restrict__ ids, const float* __restrict__ emb,
                   float* __restrict__ x_all)
{
    int q = blockIdx.x * 256 + threadIdx.x;    // 2048 rows * 128 float4
    if (q >= 2048 * 128) return;
    int r = q >> 7, kq = q & 127;
    int tgt = ids[r];
    ((float4*)x_all)[(size_t)r * 128 + kq] = ((const float4*)emb)[(size_t)tgt * 128 + kq];
}

// ---------------- hierarchical grid barrier ----------------
// Level 1: 8 arrival lines (group = k&7, 8 blocks each, RMW concurrent across lines).
// Level 2: root line (8 arrivals). Last root-arriver broadcasts per-group flags.
// Relaxed polls on own group's flag + single acquire at exit. All counters monotonic;
// entire 8KB region memset to 0 each kernel_launch call (graph-replay safe).
__device__ __forceinline__ void gbar3(int* bar, int gen)
{
    __syncthreads();
    if (threadIdx.x == 0) {
        const int g = blockIdx.x & 7;
        int a = __hip_atomic_fetch_add(bar + g * 64, 1, __ATOMIC_ACQ_REL, __HIP_MEMORY_SCOPE_AGENT);
        if (a == gen * 8 - 1) {   // last of my 8-block group for this gen
            int r = __hip_atomic_fetch_add(bar + 8 * 64, 1, __ATOMIC_ACQ_REL, __HIP_MEMORY_SCOPE_AGENT);
            if (r == gen * 8 - 1) {  // last group overall -> broadcast
#pragma unroll
                for (int gg = 0; gg < 8; ++gg)
                    __hip_atomic_store(bar + (9 + gg) * 64, gen, __ATOMIC_RELEASE, __HIP_MEMORY_SCOPE_AGENT);
            }
        }
        while (__hip_atomic_load(bar + (9 + g) * 64, __ATOMIC_RELAXED, __HIP_MEMORY_SCOPE_AGENT) < gen)
            __builtin_amdgcn_s_sleep(2);
        (void)__hip_atomic_load(bar + (9 + g) * 64, __ATOMIC_ACQUIRE, __HIP_MEMORY_SCOPE_AGENT);
    }
    __syncthreads();
}

// ---------------- persistent recurrence: 64 blocks x 1024 threads, 2 barriers/step ----
// Block k: Phase B owns batch b_own = k&15 (ctx quarter q = k>>4). The 4 blocks of a
// batch satisfy k≡b (mod 8) -> same XCD under round-robin -> keysWk/keys L2-shared.
// Phase C owns d-octet [8k, 8k+8): 32 gate rows, weights in registers (48 fp32/thread).
__global__ __launch_bounds__(1024, 4)
void recur3_kernel(const float* __restrict__ x_all, float* __restrict__ ctx,
                   float* __restrict__ h_raw2, float* __restrict__ c_g,
                   float* __restrict__ partials2,
                   const float* __restrict__ keys, const float* __restrict__ keysWk,
                   const float* __restrict__ Wih, const float* __restrict__ Whh,
                   const float* __restrict__ bih, const float* __restrict__ bhh,
                   const float* __restrict__ Wh, const float* __restrict__ lng,
                   const float* __restrict__ lnb, const float* __restrict__ vvec,
                   unsigned short* __restrict__ h_all_b, int* __restrict__ bar)
{
    __shared__ float zs[8][1536];            // 48KB: z=[x|ctx|hln] for 8 batches/pass
    __shared__ float hv[512];                // LN'd h of b_own
    __shared__ float ew[512];
    __shared__ float vv[512];
    __shared__ float sc[200], al[200];
    __shared__ float pb[8][128];
    __shared__ float gbuf[16][32];
    __shared__ float mu_s[16], rr_s[16], bias_l[32], red[32];

    const int k = blockIdx.x, tid = threadIdx.x;
    const int b_own = k & 15, q = k >> 4;
    const int rr = tid >> 5, ks = tid & 31;

    // one-time: gate-weight registers (rows j = g*512 + 8k + dd), bias, vvec
    float wreg[48];
    {
        int g = rr >> 3, dd = rr & 7;
        int j = g * 512 + 8 * k + dd;
        const float* wih_row = Wih + (size_t)j * 1024;
        const float* whh_row = Whh + (size_t)j * 512;
#pragma unroll
        for (int i = 0; i < 48; ++i) {
            int kk = ks + 32 * i;
            wreg[i] = (kk < 1024) ? wih_row[kk] : whh_row[kk - 1024];
        }
        if (tid < 32) {
            int g2 = tid >> 3, dd2 = tid & 7, j2 = g2 * 512 + 8 * k + dd2;
            bias_l[tid] = bih[j2] + bhh[j2];
        }
        if (tid < 512) vv[tid] = vvec[tid];
    }
    __syncthreads();

    int bargen = 0;
    for (int t = 0; t < T_STEPS; ++t) {
        const float* hcur = h_raw2 + (t & 1) * (BATCH * 512);
        float* hnxt = h_raw2 + ((t + 1) & 1) * (BATCH * 512);
        const float* pcur = partials2 + (t & 1) * (BATCH * 64 * 2);
        float* pnxt = partials2 + ((t + 1) & 1) * (BATCH * 64 * 2);

        // ======== Phase B: LN(b_own) + ew + scores + softmax + ctx quarter ========
        if (t > 0) {
            if (tid < 64) {
                const float* pp = pcur + ((size_t)b_own * 64 + tid) * 2;
                float s1 = pp[0], s2 = pp[1];
#pragma unroll
                for (int m = 1; m < 64; m <<= 1) { s1 += __shfl_xor(s1, m); s2 += __shfl_xor(s2, m); }
                if (tid == 0) {
                    float mu = s1 * (1.f / 512.f);
                    float var = s2 * (1.f / 512.f) - mu * mu;
                    red[0] = mu; red[1] = rsqrtf(var + 1e-5f);
                }
            }
        } else if (tid == 0) { red[0] = 0.f; red[1] = 1.f; }
        __syncthreads();
        if (tid < 128) {
            float mu_b = red[0], rr_b = red[1];
            float4 h4 = ((const float4*)(hcur + b_own * 512))[tid];
            if (t > 0) {
                float4 g4 = ((const float4*)lng)[tid], bl4 = ((const float4*)lnb)[tid];
                h4.x = (h4.x - mu_b) * rr_b * g4.x + bl4.x;
                h4.y = (h4.y - mu_b) * rr_b * g4.y + bl4.y;
                h4.z = (h4.z - mu_b) * rr_b * g4.z + bl4.z;
                h4.w = (h4.w - mu_b) * rr_b * g4.w + bl4.w;
            }
            ((float4*)hv)[tid] = h4;
        }
        __syncthreads();
        {   // ew[e] = hv . Wh[e,:] — 8 threads/e, coalesced k4 = g8 + 8i
            int g8 = tid & 7;
#pragma unroll
            for (int pass = 0; pass < 4; ++pass) {
                int e = pass * 128 + (tid >> 3);
                const float4* wr4 = (const float4*)(Wh + (size_t)e * 512);
                const float4* hh4 = (const float4*)hv;
                float s = 0.f;
#pragma unroll
                for (int i = 0; i < 16; ++i) {
                    int k4 = g8 + 8 * i;
                    float4 w4 = wr4[k4], h4 = hh4[k4];
                    s += w4.x * h4.x + w4.y * h4.y + w4.z * h4.z + w4.w * h4.w;
                }
                s += __shfl_xor(s, 1); s += __shfl_xor(s, 2); s += __shfl_xor(s, 4);
                if (g8 == 0) ew[e] = s;
            }
        }
        __syncthreads();
        {   // scores[n] = sum_d tanh(ew+kw)*v — 8 threads/n, coalesced
            int g8 = tid & 7;
#pragma unroll
            for (int pass = 0; pass < 2; ++pass) {
                int n = pass * 128 + (tid >> 3);
                if (n < NPATCH) {
                    const float4* kw4 = (const float4*)(keysWk + ((size_t)(b_own * NPATCH + n)) * 512);
                    float s = 0.f;
#pragma unroll
                    for (int i = 0; i < 16; ++i) {
                        int k4 = g8 + 8 * i;
                        float4 kk = kw4[k4];
                        int d0 = k4 * 4;
                        s += ftanh(ew[d0 + 0] + kk.x) * vv[d0 + 0]
                           + ftanh(ew[d0 + 1] + kk.y) * vv[d0 + 1]
                           + ftanh(ew[d0 + 2] + kk.z) * vv[d0 + 2]
                           + ftanh(ew[d0 + 3] + kk.w) * vv[d0 + 3];
                    }
                    s += __shfl_xor(s, 1); s += __shfl_xor(s, 2); s += __shfl_xor(s, 4);
                    if (g8 == 0) sc[n] = s;
                }
            }
        }
        __syncthreads();
        float sv = (tid < NPATCH) ? sc[tid] : -1e30f;
        {
            float m1 = sv;
#pragma unroll
            for (int m = 1; m < 64; m <<= 1) m1 = fmaxf(m1, __shfl_xor(m1, m));
            if ((tid & 63) == 0 && tid < 256) red[8 + (tid >> 6)] = m1;
        }
        __syncthreads();
        {
            float mx = fmaxf(fmaxf(red[8], red[9]), fmaxf(red[10], red[11]));
            float ev = (tid < NPATCH) ? __expf(sv - mx) : 0.f;
            if (tid < NPATCH) al[tid] = ev;
            float s2 = ev;
#pragma unroll
            for (int m = 1; m < 64; m <<= 1) s2 += __shfl_xor(s2, m);
            if ((tid & 63) == 0 && tid < 256) red[12 + (tid >> 6)] = s2;
        }
        __syncthreads();
        {   // ctx quarter: 128 d's, 8 n-groups
            float inv = 1.f / (red[12] + red[13] + red[14] + red[15]);
            int d_loc = tid & 127, g8 = tid >> 7;
            const float* kb = keys + (size_t)(b_own * NPATCH) * 512 + q * 128 + d_loc;
            float acc = 0.f;
            for (int n = g8; n < NPATCH; n += 8) acc += al[n] * kb[(size_t)n * 512];
            pb[g8][d_loc] = acc;
            __syncthreads();
            if (tid < 128) {
                float s = 0.f;
#pragma unroll
                for (int g = 0; g < 8; ++g) s += pb[g][tid];
                ctx[b_own * 512 + q * 128 + tid] = s * inv;
            }
        }
        gbar3(bar, ++bargen);

        // ======== Phase C: stats(all b) + z-stage(+h_all by block b) + gates + cell ====
        if (t > 0) {
            int bb = tid >> 6, i = tid & 63;
            const float* pp = pcur + ((size_t)bb * 64 + i) * 2;
            float s1 = pp[0], s2 = pp[1];
#pragma unroll
            for (int m = 1; m < 64; m <<= 1) { s1 += __shfl_xor(s1, m); s2 += __shfl_xor(s2, m); }
            if (i == 0) {
                float mu = s1 * (1.f / 512.f);
                float var = s2 * (1.f / 512.f) - mu * mu;
                mu_s[bb] = mu; rr_s[bb] = rsqrtf(var + 1e-5f);
            }
        } else if (tid < 16) { mu_s[tid] = 0.f; rr_s[tid] = 1.f; }
        __syncthreads();

#pragma unroll
        for (int p = 0; p < 2; ++p) {
            {   // stage 8 batches: x | ctx | hln (hln inline; h_all written only by block k==b)
                int bb = tid >> 7, kq = tid & 127;
                int b = p * 8 + bb;
                ((float4*)&zs[bb][0])[kq]   = ((const float4*)(x_all + ((size_t)b * T_STEPS + t) * 512))[kq];
                ((float4*)&zs[bb][512])[kq] = ((const float4*)(ctx + b * 512))[kq];
                float4 h4 = ((const float4*)(hcur + b * 512))[kq];
                if (t > 0) {
                    float mu = mu_s[b], rv = rr_s[b];
                    float4 g4 = ((const float4*)lng)[kq], bl4 = ((const float4*)lnb)[kq];
                    h4.x = (h4.x - mu) * rv * g4.x + bl4.x;
                    h4.y = (h4.y - mu) * rv * g4.y + bl4.y;
                    h4.z = (h4.z - mu) * rv * g4.z + bl4.z;
                    h4.w = (h4.w - mu) * rv * g4.w + bl4.w;
                    if (k == b) {
                        short4 hb = { (short)f2b(h4.x), (short)f2b(h4.y), (short)f2b(h4.z), (short)f2b(h4.w) };
                        *(short4*)(h_all_b + ((size_t)b * T_STEPS + (t - 1)) * 512 + kq * 4) = hb;
                    }
                }
                ((float4*)&zs[bb][1024])[kq] = h4;
            }
            __syncthreads();
            {   // gates: register weights x LDS z (broadcast-free scalar reads)
#pragma unroll
                for (int bl = 0; bl < 8; ++bl) {
                    float acc = 0.f;
#pragma unroll
                    for (int i = 0; i < 48; ++i) acc += wreg[i] * zs[bl][ks + 32 * i];
#pragma unroll
                    for (int m = 1; m < 32; m <<= 1) acc += __shfl_xor(acc, m);
                    if (ks == 0) gbuf[p * 8 + bl][rr] = acc;
                }
            }
            __syncthreads();
        }
        {   // cell for own 8 d's x 16 batches
            if (tid < 128) {
                int bp = tid >> 3, dd = tid & 7, d = 8 * k + dd;
                float gi = gbuf[bp][dd]      + bias_l[dd];
                float gf = gbuf[bp][8 + dd]  + bias_l[8 + dd];
                float gg = gbuf[bp][16 + dd] + bias_l[16 + dd];
                float go = gbuf[bp][24 + dd] + bias_l[24 + dd];
                float cn = sigm(gf) * c_g[bp * 512 + d] + sigm(gi) * ftanh(gg);
                c_g[bp * 512 + d] = cn;
                float hr = sigm(go) * ftanh(cn);
                hnxt[bp * 512 + d] = hr;
                float s1 = hr, s2 = hr * hr;
#pragma unroll
                for (int m = 1; m < 8; m <<= 1) { s1 += __shfl_xor(s1, m); s2 += __shfl_xor(s2, m); }
                if (dd == 0) {
                    pnxt[((size_t)bp * 64 + k) * 2 + 0] = s1;
                    pnxt[((size_t)bp * 64 + k) * 2 + 1] = s2;
                }
            }
        }
        gbar3(bar, ++bargen);
    }

    // tail: h_all row 127 = LN(h_raw); blocks 0..15 handle batch b = k
    if (k < 16) {
        const float* hcur = h_raw2 + ((T_STEPS & 1)) * (BATCH * 512);
        const float* pcur = partials2 + ((T_STEPS & 1)) * (BATCH * 64 * 2);
        int b = k;
        if (tid < 64) {
            const float* pp = pcur + ((size_t)b * 64 + tid) * 2;
            float s1 = pp[0], s2 = pp[1];
#pragma unroll
            for (int m = 1; m < 64; m <<= 1) { s1 += __shfl_xor(s1, m); s2 += __shfl_xor(s2, m); }
            if (tid == 0) {
                float mu = s1 * (1.f / 512.f);
                float var = s2 * (1.f / 512.f) - mu * mu;
                red[0] = mu; red[1] = rsqrtf(var + 1e-5f);
            }
        }
        __syncthreads();
        if (tid < 128) {
            float mu = red[0], rv = red[1];
            float4 h4 = ((const float4*)(hcur + b * 512))[tid];
            float4 g4 = ((const float4*)lng)[tid], bl4 = ((const float4*)lnb)[tid];
            h4.x = (h4.x - mu) * rv * g4.x + bl4.x;
            h4.y = (h4.y - mu) * rv * g4.y + bl4.y;
            h4.z = (h4.z - mu) * rv * g4.z + bl4.z;
            h4.w = (h4.w - mu) * rv * g4.w + bl4.w;
            short4 hb = { (short)f2b(h4.x), (short)f2b(h4.y), (short)f2b(h4.z), (short)f2b(h4.w) };
            *(short4*)(h_all_b + ((size_t)b * T_STEPS + (T_STEPS - 1)) * 512 + tid * 4) = hb;
        }
    }
}

extern "C" void kernel_launch(void* const* d_in, const int* in_sizes, int n_in,
                              void* d_out, int out_size, void* d_ws, size_t ws_size,
                              hipStream_t stream)
{
    const float* patches = (const float*)d_in[0];
    const float* cls     = (const float*)d_in[1];
    const int*   tgt     = (const int*)d_in[2];
    const float* kv_w    = (const float*)d_in[3];
    const float* kv_b    = (const float*)d_in[4];
    const float* ih_w    = (const float*)d_in[5];
    const float* ih_b    = (const float*)d_in[6];
    const float* ic_w    = (const float*)d_in[7];
    const float* ic_b    = (const float*)d_in[8];
    const float* emb     = (const float*)d_in[9];
    const float* Wh      = (const float*)d_in[10];
    const float* Wk      = (const float*)d_in[11];
    const float* av      = (const float*)d_in[12];
    const float* Wih     = (const float*)d_in[13];
    const float* Whh     = (const float*)d_in[14];
    const float* bih     = (const float*)d_in[15];
    const float* bhh     = (const float*)d_in[16];
    const float* lng     = (const float*)d_in[17];
    const float* lnb     = (const float*)d_in[18];
    const float* outw    = (const float*)d_in[19];
    const float* outb    = (const float*)d_in[20];
    float* out = (float*)d_out;

    char* wsp = (char*)d_ws;
    auto carve = [&](size_t bytes) -> char* {
        char* p = wsp; wsp += (bytes + 255) & ~(size_t)255; return p;
    };
    float*          keys_f   = (float*)carve((size_t)3136 * 512 * 4);
    float*          keysWk_f = (float*)carve((size_t)3136 * 512 * 4);
    unsigned short* keysH    = (unsigned short*)carve((size_t)3136 * 512 * 2);
    unsigned short* keysL    = (unsigned short*)carve((size_t)3136 * 512 * 2);
    float*          x_all_f  = (float*)carve((size_t)2048 * 512 * 4);
    unsigned short* h_all_b  = (unsigned short*)carve((size_t)2048 * 512 * 2);
    unsigned short* kvwH     = (unsigned short*)carve((size_t)512 * 768 * 2);
    unsigned short* kvwL     = (unsigned short*)carve((size_t)512 * 768 * 2);
    unsigned short* wkH      = (unsigned short*)carve((size_t)512 * 512 * 2);
    unsigned short* wkL      = (unsigned short*)carve((size_t)512 * 512 * 2);
    unsigned short* outw_b   = (unsigned short*)carve((size_t)VOCAB * 512 * 2);  // 10.24 MB
    float* ctx      = (float*)carve((size_t)16 * 512 * 4);
    float* h_raw2   = (float*)carve((size_t)2 * 16 * 512 * 4);
    float* c_g      = (float*)carve((size_t)16 * 512 * 4);
    float* partials2= (float*)carve((size_t)2 * 16 * 64 * 2 * 4);
    int*   bar      = (int*)carve(8192);   // 17 lines x 256B, all memset each call
    // patches split aliases outw_b; outw converted after keys GEMM.
    unsigned short* patH = outw_b;
    unsigned short* patL = outw_b + (size_t)3136 * 768;

    hipMemsetAsync(bar, 0, 8192, stream);

    auto cvt = [&](const float* s, unsigned short* d, int n) {
        cvt_kernel<<<(n / 8 + 255) / 256, 256, 0, stream>>>(s, d, n);
    };
    auto cvts = [&](const float* s, unsigned short* dh, unsigned short* dl, int n) {
        cvt_split_kernel<<<(n / 8 + 255) / 256, 256, 0, stream>>>(s, dh, dl, n);
    };
    cvts(patches, patH, patL, 3136 * 768);
    cvts(kv_w, kvwH, kvwL, 512 * 768);
    cvts(Wk, wkH, wkL, 512 * 512);

    // keys = patches @ kv_w^T + kv_b : fp32 + split-bf16 outputs
    gemm_mfma<<<dim3(25, 4), 256, 0, stream>>>(patH, patL, kvwH, kvwL, kv_b,
                                               keys_f, keysH, keysL, 3136, 512, 768);
    // patches region free now: convert outw into it
    cvt(outw, outw_b, VOCAB * 512);
    // keysWk = keys @ Wk^T : fp32 out
    gemm_mfma<<<dim3(25, 4), 256, 0, stream>>>(keysH, keysL, wkH, wkL, nullptr,
                                               keysWk_f, nullptr, nullptr, 3136, 512, 512);

    h0c0_kernel<<<64, 256, 0, stream>>>(cls, ih_w, ih_b, ic_w, ic_b, c_g, h_raw2);
    gather_kernel<<<1024, 256, 0, stream>>>(tgt, emb, x_all_f);

    // persistent recurrence: 64 blocks x 1024 threads, 2 hierarchical barriers/step
    recur3_kernel<<<NB3, 1024, 0, stream>>>(x_all_f, ctx, h_raw2, c_g, partials2,
                                            keys_f, keysWk_f, Wih, Whh, bih, bhh, Wh,
                                            lng, lnb, av, h_all_b, bar);

    // logits = h_all @ outw^T + out_b  (bf16 MFMA, fp32 out)
    gemm_mfma<<<dim3(16, 79), 256, 0, stream>>>(h_all_b, nullptr, outw_b, nullptr, outb,
                                                out, nullptr, nullptr, 2048, VOCAB, 512);
}

// Round 10
// 11905.301 us; speedup vs baseline: 1.1947x; 1.0479x over previous
//
#include <hip/hip_runtime.h>
#include <hip/hip_bf16.h>

#define T_STEPS 128
#define DH      512
#define NPATCH  196
#define BATCH   16
#define VOCAB   10000
#define NB3     64     // persistent grid: 64 blocks x 1024 threads

typedef __attribute__((ext_vector_type(8))) short bf16x8;
typedef __attribute__((ext_vector_type(4))) float f32x4;

__device__ __forceinline__ float sigm(float x) { return 1.0f / (1.0f + __expf(-x)); }
__device__ __forceinline__ float ftanh(float x) {
    float e = __expf(2.0f * x);
    return 1.0f - 2.0f / (e + 1.0f);
}
__device__ __forceinline__ unsigned short f2b(float x) {
    union { float f; unsigned u; } v; v.f = x;
    unsigned r = (v.u + 0x7FFFu + ((v.u >> 16) & 1u)) >> 16;
    return (unsigned short)r;
}
__device__ __forceinline__ float b2f(unsigned short h) {
    union { unsigned u; float f; } v; v.u = ((unsigned)h) << 16;
    return v.f;
}

// Coherent cross-XCD access WITHOUT cache-invalidating fences: relaxed agent-scope
// atomics compile to sc0/sc1 cache-bypassing ops (visible at L3 coherence point).
// Ordering is provided by __syncthreads() which drains vmcnt(0) before s_barrier.
__device__ __forceinline__ float cload(const float* p) {
    return __hip_atomic_load(p, __ATOMIC_RELAXED, __HIP_MEMORY_SCOPE_AGENT);
}
__device__ __forceinline__ void cstore(float* p, float v) {
    __hip_atomic_store(p, v, __ATOMIC_RELAXED, __HIP_MEMORY_SCOPE_AGENT);
}

// ---------------- conversion kernels ----------------
__global__ __launch_bounds__(256)
void cvt_kernel(const float* __restrict__ src, unsigned short* __restrict__ dst, int n)
{
    int i = (blockIdx.x * 256 + threadIdx.x) * 8;
    if (i >= n) return;
    float4 v0 = *(const float4*)(src + i);
    float4 v1 = *(const float4*)(src + i + 4);
    float xs[8] = {v0.x, v0.y, v0.z, v0.w, v1.x, v1.y, v1.z, v1.w};
    bf16x8 o;
#pragma unroll
    for (int j = 0; j < 8; ++j) o[j] = (short)f2b(xs[j]);
    *(bf16x8*)(dst + i) = o;
}

__global__ __launch_bounds__(256)
void cvt_split_kernel(const float* __restrict__ src, unsigned short* __restrict__ hi,
                      unsigned short* __restrict__ lo, int n)
{
    int i = (blockIdx.x * 256 + threadIdx.x) * 8;
    if (i >= n) return;
    float4 v0 = *(const float4*)(src + i);
    float4 v1 = *(const float4*)(src + i + 4);
    float xs[8] = {v0.x, v0.y, v0.z, v0.w, v1.x, v1.y, v1.z, v1.w};
    bf16x8 h_, l_;
#pragma unroll
    for (int j = 0; j < 8; ++j) {
        unsigned short hb = f2b(xs[j]);
        float r = xs[j] - b2f(hb);
        h_[j] = (short)hb;
        l_[j] = (short)f2b(r);
    }
    *(bf16x8*)(hi + i) = h_;
    *(bf16x8*)(lo + i) = l_;
}

// ---------------- MFMA GEMM (3-term split; verified round 4) ----------------
__global__ __launch_bounds__(256)
void gemm_mfma(const unsigned short* __restrict__ AH, const unsigned short* __restrict__ AL,
               const unsigned short* __restrict__ WH, const unsigned short* __restrict__ WL,
               const float* __restrict__ bias, float* __restrict__ C,
               unsigned short* __restrict__ CbH, unsigned short* __restrict__ CbL,
               int M, int N, int K)
{
    const int tid = threadIdx.x, wid = tid >> 6, l = tid & 63;
    const int m0 = blockIdx.x * 128 + (wid >> 1) * 64;
    const int n0 = blockIdx.y * 128 + (wid & 1) * 64;
    const int lm = l & 15, lk = (l >> 4) * 8;
    f32x4 acc[4][4];
#pragma unroll
    for (int i = 0; i < 4; ++i)
#pragma unroll
        for (int j = 0; j < 4; ++j) acc[i][j] = (f32x4){0.f, 0.f, 0.f, 0.f};
    const bf16x8 az = {0,0,0,0,0,0,0,0};

    for (int k0 = 0; k0 < K; k0 += 32) {
        bf16x8 aH[4], aL[4];
#pragma unroll
        for (int mi = 0; mi < 4; ++mi) {
            int m = m0 + mi * 16 + lm;
            aH[mi] = (m < M) ? *(const bf16x8*)(AH + (size_t)m * K + k0 + lk) : az;
            aL[mi] = (AL && m < M) ? *(const bf16x8*)(AL + (size_t)m * K + k0 + lk) : az;
        }
#pragma unroll
        for (int ni = 0; ni < 4; ++ni) {
            int n = n0 + ni * 16 + lm;
            bf16x8 bH = az, bL = az;
            if (n < N) {
                bH = *(const bf16x8*)(WH + (size_t)n * K + k0 + lk);
                if (WL) bL = *(const bf16x8*)(WL + (size_t)n * K + k0 + lk);
            }
#pragma unroll
            for (int mi = 0; mi < 4; ++mi) {
                acc[mi][ni] = __builtin_amdgcn_mfma_f32_16x16x32_bf16(aH[mi], bH, acc[mi][ni], 0, 0, 0);
                if (WL) acc[mi][ni] = __builtin_amdgcn_mfma_f32_16x16x32_bf16(aH[mi], bL, acc[mi][ni], 0, 0, 0);
                if (AL) acc[mi][ni] = __builtin_amdgcn_mfma_f32_16x16x32_bf16(aL[mi], bH, acc[mi][ni], 0, 0, 0);
            }
        }
    }
    const int rr = (l >> 4) * 4;
#pragma unroll
    for (int mi = 0; mi < 4; ++mi) {
        int mb = m0 + mi * 16 + rr;
#pragma unroll
        for (int ni = 0; ni < 4; ++ni) {
            int n = n0 + ni * 16 + lm;
            if (n < N) {
                float bs = bias ? bias[n] : 0.f;
#pragma unroll
                for (int r = 0; r < 4; ++r) {
                    int mm = mb + r;
                    if (mm < M) {
                        float v = acc[mi][ni][r] + bs;
                        if (C)   C[(size_t)mm * N + n] = v;
                        if (CbH) {
                            unsigned short hb = f2b(v);
                            CbH[(size_t)mm * N + n] = hb;
                            if (CbL) CbL[(size_t)mm * N + n] = f2b(v - b2f(hb));
                        }
                    }
                }
            }
        }
    }
}

// ---------------- h0 / c0 (fp32) ----------------
__global__ __launch_bounds__(256)
void h0c0_kernel(const float* __restrict__ cls,
                 const float* __restrict__ ihw, const float* __restrict__ ihb,
                 const float* __restrict__ icw, const float* __restrict__ icb,
                 float* __restrict__ c_g, float* __restrict__ h_raw0)
{
    int id = blockIdx.x * 256 + threadIdx.x;   // 0..16383
    int which = id >> 13;
    int b = (id >> 9) & 15;
    int d = id & 511;
    const float* w = (which ? icw : ihw) + d * 768;
    const float* x = cls + b * 768;
    float acc = which ? icb[d] : ihb[d];
    const float4* x4 = (const float4*)x;
    const float4* w4 = (const float4*)w;
#pragma unroll 4
    for (int k = 0; k < 192; ++k) {
        float4 a = x4[k], ww = w4[k];
        acc += a.x * ww.x + a.y * ww.y + a.z * ww.z + a.w * ww.w;
    }
    if (which) c_g[b * 512 + d] = acc;
    else h_raw0[b * 512 + d] = acc;
}

// ---------------- embedding gather (fp32) ----------------
__global__ __launch_bounds__(256)
void gather_kernel(const int* __restrict__ ids, const float* __restrict__ emb,
                   float* __restrict__ x_all)
{
    int q = blockIdx.x * 256 + threadIdx.x;    // 2048 rows * 128 float4
    if (q >= 2048 * 128) return;
    int r = q >> 7, kq = q & 127;
    int tgt = ids[r];
    ((float4*)x_all)[(size_t)r * 128 + kq] = ((const float4*)emb)[(size_t)tgt * 128 + kq];
}

// ---------------- hierarchical grid barrier — ALL RELAXED ----------------
// No acquire/release anywhere: relaxed ops don't emit L2 invalidates (the r9 killer:
// agent-scope acquire invalidates the non-cross-coherent per-XCD L2 -> 54MB/step refetch).
// Correctness: __syncthreads() drains vmcnt(0) before s_barrier, so every block's
// write-through (sc1) data stores are at the L3 coherence point BEFORE its arrival RMW;
// the flag is causally after all 64 arrivals. Data reads use cload (bypass L1/L2).
__device__ __forceinline__ void gbar3(int* bar, int gen)
{
    __syncthreads();   // drains this block's stores (vmcnt(0) before s_barrier)
    if (threadIdx.x == 0) {
        const int g = blockIdx.x & 7;
        int a = __hip_atomic_fetch_add(bar + g * 64, 1, __ATOMIC_RELAXED, __HIP_MEMORY_SCOPE_AGENT);
        if (a == gen * 8 - 1) {   // last of my 8-block group for this gen
            int r = __hip_atomic_fetch_add(bar + 8 * 64, 1, __ATOMIC_RELAXED, __HIP_MEMORY_SCOPE_AGENT);
            if (r == gen * 8 - 1) {  // last group overall -> broadcast
#pragma unroll
                for (int gg = 0; gg < 8; ++gg)
                    __hip_atomic_store(bar + (9 + gg) * 64, gen, __ATOMIC_RELAXED, __HIP_MEMORY_SCOPE_AGENT);
            }
        }
        while (__hip_atomic_load(bar + (9 + g) * 64, __ATOMIC_RELAXED, __HIP_MEMORY_SCOPE_AGENT) < gen)
            __builtin_amdgcn_s_sleep(2);
    }
    __syncthreads();
}

// ---------------- persistent recurrence: 64 blocks x 1024 threads, 2 barriers/step ----
// Cross-block buffers (ctx, h_raw2, partials2) via cload/cstore ONLY.
// Read-only streams (Wh, keysWk, keys, x_all) via normal cached loads — stay L2-hot.
__global__ __launch_bounds__(1024, 4)
void recur4_kernel(const float* __restrict__ x_all, float* __restrict__ ctx,
                   float* __restrict__ h_raw2, float* __restrict__ c_g,
                   float* __restrict__ partials2,
                   const float* __restrict__ keys, const float* __restrict__ keysWk,
                   const float* __restrict__ Wih, const float* __restrict__ Whh,
                   const float* __restrict__ bih, const float* __restrict__ bhh,
                   const float* __restrict__ Wh, const float* __restrict__ lng,
                   const float* __restrict__ lnb, const float* __restrict__ vvec,
                   unsigned short* __restrict__ h_all_b, int* __restrict__ bar)
{
    __shared__ float zs[8][1536];            // 48KB: z=[x|ctx|hln] for 8 batches/pass
    __shared__ float hv[512];                // LN'd h of b_own
    __shared__ float ew[512];
    __shared__ float vv[512];
    __shared__ float sc[200], al[200];
    __shared__ float pb[8][128];
    __shared__ float gbuf[16][32];
    __shared__ float mu_s[16], rr_s[16], bias_l[32], red[32];

    const int k = blockIdx.x, tid = threadIdx.x;
    const int b_own = k & 15, q = k >> 4;
    const int rr = tid >> 5, ks = tid & 31;

    // one-time: gate-weight registers (rows j = g*512 + 8k + dd), bias, vvec
    float wreg[48];
    {
        int g = rr >> 3, dd = rr & 7;
        int j = g * 512 + 8 * k + dd;
        const float* wih_row = Wih + (size_t)j * 1024;
        const float* whh_row = Whh + (size_t)j * 512;
#pragma unroll
        for (int i = 0; i < 48; ++i) {
            int kk = ks + 32 * i;
            wreg[i] = (kk < 1024) ? wih_row[kk] : whh_row[kk - 1024];
        }
        if (tid < 32) {
            int g2 = tid >> 3, dd2 = tid & 7, j2 = g2 * 512 + 8 * k + dd2;
            bias_l[tid] = bih[j2] + bhh[j2];
        }
        if (tid < 512) vv[tid] = vvec[tid];
    }
    __syncthreads();

    int bargen = 0;
    for (int t = 0; t < T_STEPS; ++t) {
        const float* hcur = h_raw2 + (t & 1) * (BATCH * 512);
        float* hnxt = h_raw2 + ((t + 1) & 1) * (BATCH * 512);
        const float* pcur = partials2 + (t & 1) * (BATCH * 64 * 2);
        float* pnxt = partials2 + ((t + 1) & 1) * (BATCH * 64 * 2);

        // ======== Phase B: LN(b_own) + ew + scores + softmax + ctx quarter ========
        if (t > 0) {
            if (tid < 64) {
                const float* pp = pcur + ((size_t)b_own * 64 + tid) * 2;
                float s1 = cload(pp), s2 = cload(pp + 1);
#pragma unroll
                for (int m = 1; m < 64; m <<= 1) { s1 += __shfl_xor(s1, m); s2 += __shfl_xor(s2, m); }
                if (tid == 0) {
                    float mu = s1 * (1.f / 512.f);
                    float var = s2 * (1.f / 512.f) - mu * mu;
                    red[0] = mu; red[1] = rsqrtf(var + 1e-5f);
                }
            }
        } else if (tid == 0) { red[0] = 0.f; red[1] = 1.f; }
        __syncthreads();
        if (tid < 128) {
            float mu_b = red[0], rr_b = red[1];
            int base = b_own * 512 + tid * 4;
            float4 h4;
            h4.x = cload(hcur + base + 0); h4.y = cload(hcur + base + 1);
            h4.z = cload(hcur + base + 2); h4.w = cload(hcur + base + 3);
            if (t > 0) {
                float4 g4 = ((const float4*)lng)[tid], bl4 = ((const float4*)lnb)[tid];
                h4.x = (h4.x - mu_b) * rr_b * g4.x + bl4.x;
                h4.y = (h4.y - mu_b) * rr_b * g4.y + bl4.y;
                h4.z = (h4.z - mu_b) * rr_b * g4.z + bl4.z;
                h4.w = (h4.w - mu_b) * rr_b * g4.w + bl4.w;
            }
            ((float4*)hv)[tid] = h4;
        }
        __syncthreads();
        {   // ew[e] = hv . Wh[e,:] — 8 threads/e, coalesced k4 = g8 + 8i
            int g8 = tid & 7;
#pragma unroll
            for (int pass = 0; pass < 4; ++pass) {
                int e = pass * 128 + (tid >> 3);
                const float4* wr4 = (const float4*)(Wh + (size_t)e * 512);
                const float4* hh4 = (const float4*)hv;
                float s = 0.f;
#pragma unroll
                for (int i = 0; i < 16; ++i) {
                    int k4 = g8 + 8 * i;
                    float4 w4 = wr4[k4], h4 = hh4[k4];
                    s += w4.x * h4.x + w4.y * h4.y + w4.z * h4.z + w4.w * h4.w;
                }
                s += __shfl_xor(s, 1); s += __shfl_xor(s, 2); s += __shfl_xor(s, 4);
                if (g8 == 0) ew[e] = s;
            }
        }
        __syncthreads();
        {   // scores[n] = sum_d tanh(ew+kw)*v — 8 threads/n, coalesced
            int g8 = tid & 7;
#pragma unroll
            for (int pass = 0; pass < 2; ++pass) {
                int n = pass * 128 + (tid >> 3);
                if (n < NPATCH) {
                    const float4* kw4 = (const float4*)(keysWk + ((size_t)(b_own * NPATCH + n)) * 512);
                    float s = 0.f;
#pragma unroll
                    for (int i = 0; i < 16; ++i) {
                        int k4 = g8 + 8 * i;
                        float4 kk = kw4[k4];
                        int d0 = k4 * 4;
                        s += ftanh(ew[d0 + 0] + kk.x) * vv[d0 + 0]
                           + ftanh(ew[d0 + 1] + kk.y) * vv[d0 + 1]
                           + ftanh(ew[d0 + 2] + kk.z) * vv[d0 + 2]
                           + ftanh(ew[d0 + 3] + kk.w) * vv[d0 + 3];
                    }
                    s += __shfl_xor(s, 1); s += __shfl_xor(s, 2); s += __shfl_xor(s, 4);
                    if (g8 == 0) sc[n] = s;
                }
            }
        }
        __syncthreads();
        float sv = (tid < NPATCH) ? sc[tid] : -1e30f;
        {
            float m1 = sv;
#pragma unroll
            for (int m = 1; m < 64; m <<= 1) m1 = fmaxf(m1, __shfl_xor(m1, m));
            if ((tid & 63) == 0 && tid < 256) red[8 + (tid >> 6)] = m1;
        }
        __syncthreads();
        {
            float mx = fmaxf(fmaxf(red[8], red[9]), fmaxf(red[10], red[11]));
            float ev = (tid < NPATCH) ? __expf(sv - mx) : 0.f;
            if (tid < NPATCH) al[tid] = ev;
            float s2 = ev;
#pragma unroll
            for (int m = 1; m < 64; m <<= 1) s2 += __shfl_xor(s2, m);
            if ((tid & 63) == 0 && tid < 256) red[12 + (tid >> 6)] = s2;
        }
        __syncthreads();
        {   // ctx quarter: 128 d's, 8 n-groups (keys = normal cached loads)
            float inv = 1.f / (red[12] + red[13] + red[14] + red[15]);
            int d_loc = tid & 127, g8 = tid >> 7;
            const float* kb = keys + (size_t)(b_own * NPATCH) * 512 + q * 128 + d_loc;
            float acc = 0.f;
            for (int n = g8; n < NPATCH; n += 8) acc += al[n] * kb[(size_t)n * 512];
            pb[g8][d_loc] = acc;
            __syncthreads();
            if (tid < 128) {
                float s = 0.f;
#pragma unroll
                for (int g = 0; g < 8; ++g) s += pb[g][tid];
                cstore(&ctx[b_own * 512 + q * 128 + tid], s * inv);
            }
        }
        gbar3(bar, ++bargen);

        // ======== Phase C: stats(all b) + z-stage(+h_all by block b) + gates + cell ====
        if (t > 0) {
            int bb = tid >> 6, i = tid & 63;
            const float* pp = pcur + ((size_t)bb * 64 + i) * 2;
            float s1 = cload(pp), s2 = cload(pp + 1);
#pragma unroll
            for (int m = 1; m < 64; m <<= 1) { s1 += __shfl_xor(s1, m); s2 += __shfl_xor(s2, m); }
            if (i == 0) {
                float mu = s1 * (1.f / 512.f);
                float var = s2 * (1.f / 512.f) - mu * mu;
                mu_s[bb] = mu; rr_s[bb] = rsqrtf(var + 1e-5f);
            }
        } else if (tid < 16) { mu_s[tid] = 0.f; rr_s[tid] = 1.f; }
        __syncthreads();

#pragma unroll
        for (int p = 0; p < 2; ++p) {
            {   // stage 8 batches: x (cached) | ctx (cload) | hln (cload + inline LN)
                int bb = tid >> 7, kq = tid & 127;
                int b = p * 8 + bb;
                ((float4*)&zs[bb][0])[kq] = ((const float4*)(x_all + ((size_t)b * T_STEPS + t) * 512))[kq];
                int cbase = b * 512 + kq * 4;
                float4 c4;
                c4.x = cload(ctx + cbase + 0); c4.y = cload(ctx + cbase + 1);
                c4.z = cload(ctx + cbase + 2); c4.w = cload(ctx + cbase + 3);
                ((float4*)&zs[bb][512])[kq] = c4;
                float4 h4;
                h4.x = cload(hcur + cbase + 0); h4.y = cload(hcur + cbase + 1);
                h4.z = cload(hcur + cbase + 2); h4.w = cload(hcur + cbase + 3);
                if (t > 0) {
                    float mu = mu_s[b], rv = rr_s[b];
                    float4 g4 = ((const float4*)lng)[kq], bl4 = ((const float4*)lnb)[kq];
                    h4.x = (h4.x - mu) * rv * g4.x + bl4.x;
                    h4.y = (h4.y - mu) * rv * g4.y + bl4.y;
                    h4.z = (h4.z - mu) * rv * g4.z + bl4.z;
                    h4.w = (h4.w - mu) * rv * g4.w + bl4.w;
                    if (k == b) {
                        short4 hb = { (short)f2b(h4.x), (short)f2b(h4.y), (short)f2b(h4.z), (short)f2b(h4.w) };
                        *(short4*)(h_all_b + ((size_t)b * T_STEPS + (t - 1)) * 512 + kq * 4) = hb;
                    }
                }
                ((float4*)&zs[bb][1024])[kq] = h4;
            }
            __syncthreads();
            {   // gates: register weights x LDS z
#pragma unroll
                for (int bl = 0; bl < 8; ++bl) {
                    float acc = 0.f;
#pragma unroll
                    for (int i = 0; i < 48; ++i) acc += wreg[i] * zs[bl][ks + 32 * i];
#pragma unroll
                    for (int m = 1; m < 32; m <<= 1) acc += __shfl_xor(acc, m);
                    if (ks == 0) gbuf[p * 8 + bl][rr] = acc;
                }
            }
            __syncthreads();
        }
        {   // cell for own 8 d's x 16 batches
            if (tid < 128) {
                int bp = tid >> 3, dd = tid & 7, d = 8 * k + dd;
                float gi = gbuf[bp][dd]      + bias_l[dd];
                float gf = gbuf[bp][8 + dd]  + bias_l[8 + dd];
                float gg = gbuf[bp][16 + dd] + bias_l[16 + dd];
                float go = gbuf[bp][24 + dd] + bias_l[24 + dd];
                float cn = sigm(gf) * c_g[bp * 512 + d] + sigm(gi) * ftanh(gg);
                c_g[bp * 512 + d] = cn;             // block-private: normal store
                float hr = sigm(go) * ftanh(cn);
                cstore(&hnxt[bp * 512 + d], hr);
                float s1 = hr, s2 = hr * hr;
#pragma unroll
                for (int m = 1; m < 8; m <<= 1) { s1 += __shfl_xor(s1, m); s2 += __shfl_xor(s2, m); }
                if (dd == 0) {
                    cstore(&pnxt[((size_t)bp * 64 + k) * 2 + 0], s1);
                    cstore(&pnxt[((size_t)bp * 64 + k) * 2 + 1], s2);
                }
            }
        }
        gbar3(bar, ++bargen);
    }

    // tail: h_all row 127 = LN(h_raw); blocks 0..15 handle batch b = k
    if (k < 16) {
        const float* hcur = h_raw2 + ((T_STEPS & 1)) * (BATCH * 512);
        const float* pcur = partials2 + ((T_STEPS & 1)) * (BATCH * 64 * 2);
        int b = k;
        if (tid < 64) {
            const float* pp = pcur + ((size_t)b * 64 + tid) * 2;
            float s1 = cload(pp), s2 = cload(pp + 1);
#pragma unroll
            for (int m = 1; m < 64; m <<= 1) { s1 += __shfl_xor(s1, m); s2 += __shfl_xor(s2, m); }
            if (tid == 0) {
                float mu = s1 * (1.f / 512.f);
                float var = s2 * (1.f / 512.f) - mu * mu;
                red[0] = mu; red[1] = rsqrtf(var + 1e-5f);
            }
        }
        __syncthreads();
        if (tid < 128) {
            float mu = red[0], rv = red[1];
            int base = b * 512 + tid * 4;
            float4 h4;
            h4.x = cload(hcur + base + 0); h4.y = cload(hcur + base + 1);
            h4.z = cload(hcur + base + 2); h4.w = cload(hcur + base + 3);
            float4 g4 = ((const float4*)lng)[tid], bl4 = ((const float4*)lnb)[tid];
            h4.x = (h4.x - mu) * rv * g4.x + bl4.x;
            h4.y = (h4.y - mu) * rv * g4.y + bl4.y;
            h4.z = (h4.z - mu) * rv * g4.z + bl4.z;
            h4.w = (h4.w - mu) * rv * g4.w + bl4.w;
            short4 hb = { (short)f2b(h4.x), (short)f2b(h4.y), (short)f2b(h4.z), (short)f2b(h4.w) };
            *(short4*)(h_all_b + ((size_t)b * T_STEPS + (T_STEPS - 1)) * 512 + tid * 4) = hb;
        }
    }
}

extern "C" void kernel_launch(void* const* d_in, const int* in_sizes, int n_in,
                              void* d_out, int out_size, void* d_ws, size_t ws_size,
                              hipStream_t stream)
{
    const float* patches = (const float*)d_in[0];
    const float* cls     = (const float*)d_in[1];
    const int*   tgt     = (const int*)d_in[2];
    const float* kv_w    = (const float*)d_in[3];
    const float* kv_b    = (const float*)d_in[4];
    const float* ih_w    = (const float*)d_in[5];
    const float* ih_b    = (const float*)d_in[6];
    const float* ic_w    = (const float*)d_in[7];
    const float* ic_b    = (const float*)d_in[8];
    const float* emb     = (const float*)d_in[9];
    const float* Wh      = (const float*)d_in[10];
    const float* Wk      = (const float*)d_in[11];
    const float* av      = (const float*)d_in[12];
    const float* Wih     = (const float*)d_in[13];
    const float* Whh     = (const float*)d_in[14];
    const float* bih     = (const float*)d_in[15];
    const float* bhh     = (const float*)d_in[16];
    const float* lng     = (const float*)d_in[17];
    const float* lnb     = (const float*)d_in[18];
    const float* outw    = (const float*)d_in[19];
    const float* outb    = (const float*)d_in[20];
    float* out = (float*)d_out;

    char* wsp = (char*)d_ws;
    auto carve = [&](size_t bytes) -> char* {
        char* p = wsp; wsp += (bytes + 255) & ~(size_t)255; return p;
    };
    float*          keys_f   = (float*)carve((size_t)3136 * 512 * 4);
    float*          keysWk_f = (float*)carve((size_t)3136 * 512 * 4);
    unsigned short* keysH    = (unsigned short*)carve((size_t)3136 * 512 * 2);
    unsigned short* keysL    = (unsigned short*)carve((size_t)3136 * 512 * 2);
    float*          x_all_f  = (float*)carve((size_t)2048 * 512 * 4);
    unsigned short* h_all_b  = (unsigned short*)carve((size_t)2048 * 512 * 2);
    unsigned short* kvwH     = (unsigned short*)carve((size_t)512 * 768 * 2);
    unsigned short* kvwL     = (unsigned short*)carve((size_t)512 * 768 * 2);
    unsigned short* wkH      = (unsigned short*)carve((size_t)512 * 512 * 2);
    unsigned short* wkL      = (unsigned short*)carve((size_t)512 * 512 * 2);
    unsigned short* outw_b   = (unsigned short*)carve((size_t)VOCAB * 512 * 2);  // 10.24 MB
    float* ctx      = (float*)carve((size_t)16 * 512 * 4);
    float* h_raw2   = (float*)carve((size_t)2 * 16 * 512 * 4);
    float* c_g      = (float*)carve((size_t)16 * 512 * 4);
    float* partials2= (float*)carve((size_t)2 * 16 * 64 * 2 * 4);
    int*   bar      = (int*)carve(8192);   // 17 lines x 256B, all memset each call
    // patches split aliases outw_b; outw converted after keys GEMM.
    unsigned short* patH = outw_b;
    unsigned short* patL = outw_b + (size_t)3136 * 768;

    hipMemsetAsync(bar, 0, 8192, stream);

    auto cvt = [&](const float* s, unsigned short* d, int n) {
        cvt_kernel<<<(n / 8 + 255) / 256, 256, 0, stream>>>(s, d, n);
    };
    auto cvts = [&](const float* s, unsigned short* dh, unsigned short* dl, int n) {
        cvt_split_kernel<<<(n / 8 + 255) / 256, 256, 0, stream>>>(s, dh, dl, n);
    };
    cvts(patches, patH, patL, 3136 * 768);
    cvts(kv_w, kvwH, kvwL, 512 * 768);
    cvts(Wk, wkH, wkL, 512 * 512);

    // keys = patches @ kv_w^T + kv_b : fp32 + split-bf16 outputs
    gemm_mfma<<<dim3(25, 4), 256, 0, stream>>>(patH, patL, kvwH, kvwL, kv_b,
                                               keys_f, keysH, keysL, 3136, 512, 768);
    // patches region free now: convert outw into it
    cvt(outw, outw_b, VOCAB * 512);
    // keysWk = keys @ Wk^T : fp32 out
    gemm_mfma<<<dim3(25, 4), 256, 0, stream>>>(keysH, keysL, wkH, wkL, nullptr,
                                               keysWk_f, nullptr, nullptr, 3136, 512, 512);

    h0c0_kernel<<<64, 256, 0, stream>>>(cls, ih_w, ih_b, ic_w, ic_b, c_g, h_raw2);
    gather_kernel<<<1024, 256, 0, stream>>>(tgt, emb, x_all_f);

    // persistent recurrence: 64 blocks x 1024 threads, relaxed-coherence exchange
    recur4_kernel<<<NB3, 1024, 0, stream>>>(x_all_f, ctx, h_raw2, c_g, partials2,
                                            keys_f, keysWk_f, Wih, Whh, bih, bhh, Wh,
                                            lng, lnb, av, h_all_b, bar);

    // logits = h_all @ outw^T + out_b  (bf16 MFMA, fp32 out)
    gemm_mfma<<<dim3(16, 79), 256, 0, stream>>>(h_all_b, nullptr, outw_b, nullptr, outb,
                                                out, nullptr, nullptr, 2048, VOCAB, 512);
}